// Round 1
// baseline (699.303 us; speedup 1.0000x reference)
//
#include <hip/hip_runtime.h>

// Problem constants: B=8, C=128, H=W=64, G=8, K=9, Cg=16, Cd=64
// Pixel layout NCHW, HW = 4096.

// ---------------- generic weight transpose: dst[ct*stride + o] = src[o*CT + ct]
__global__ __launch_bounds__(256) void k_transpose(const float* __restrict__ src,
        float* __restrict__ dst, int O, int CT, int stride) {
    int i = blockIdx.x * 256 + threadIdx.x;
    if (i >= CT * stride) return;
    int ct = i / stride;
    int o = i - ct * stride;
    dst[i] = (o < O) ? src[o * CT + ct] : 0.0f;
}

// ---------------- k1: feat_arm = relu(W_fsm . feat_l * s + b)   Cin=128 Cout=128
__global__ __launch_bounds__(256) void k_fsm(const float* __restrict__ x,
        const float* __restrict__ Wt, const float* __restrict__ sc,
        const float* __restrict__ bi, float* __restrict__ out) {
    __shared__ float X[128 * 64];
    const int t = threadIdx.x;
    const int pb = blockIdx.x * 64;        // 512 blocks x 64 px
    const int b = pb >> 12;
    const int hw0 = pb & 4095;
    for (int i = t; i < 128 * 64; i += 256) {
        int c = i >> 6, px = i & 63;
        X[i] = x[((b << 7) + c) * 4096 + hw0 + px];
    }
    __syncthreads();
    const int lane = t & 63;
    const int wid = __builtin_amdgcn_readfirstlane(t >> 6);
    const int o0 = wid * 32;
    float acc[32];
#pragma unroll
    for (int j = 0; j < 32; j++) acc[j] = 0.0f;
    for (int c = 0; c < 128; c++) {
        float xv = X[(c << 6) + lane];
        const float* wr = (const float*)__builtin_assume_aligned(Wt + (c << 7) + o0, 16);
#pragma unroll
        for (int j = 0; j < 32; j++) acc[j] = fmaf(xv, wr[j], acc[j]);
    }
#pragma unroll
    for (int j = 0; j < 32; j++) {
        int o = o0 + j;
        float v = fmaf(acc[j], sc[o], bi[o]);
        out[((b << 7) + o) * 4096 + hw0 + lane] = v > 0.0f ? v : 0.0f;
    }
}

// ---------------- k2: offset = relu(W_off . concat(feat_arm, 2*feat_up) * s + b)  Cin=256 Cout=128
__global__ __launch_bounds__(256) void k_off(const float* __restrict__ arm,
        const float* __restrict__ fs, const float* __restrict__ Wt,
        const float* __restrict__ sc, const float* __restrict__ bi,
        float* __restrict__ out) {
    __shared__ float X[256 * 64];
    const int t = threadIdx.x;
    const int pb = blockIdx.x * 64;
    const int b = pb >> 12;
    const int hw0 = pb & 4095;
    const int h = hw0 >> 6;                 // uniform: block covers one row
    for (int i = t; i < 256 * 64; i += 256) {
        int c = i >> 6, px = i & 63;
        float v;
        if (c < 128) {
            v = arm[((b << 7) + c) * 4096 + hw0 + px];
        } else {
            int cc = c - 128;
            v = 2.0f * fs[((b << 7) + cc) * 1024 + ((h >> 1) << 5) + (px >> 1)];
        }
        X[i] = v;
    }
    __syncthreads();
    const int lane = t & 63;
    const int wid = __builtin_amdgcn_readfirstlane(t >> 6);
    const int o0 = wid * 32;
    float acc[32];
#pragma unroll
    for (int j = 0; j < 32; j++) acc[j] = 0.0f;
    for (int c = 0; c < 256; c++) {
        float xv = X[(c << 6) + lane];
        const float* wr = (const float*)__builtin_assume_aligned(Wt + (c << 7) + o0, 16);
#pragma unroll
        for (int j = 0; j < 32; j++) acc[j] = fmaf(xv, wr[j], acc[j]);
    }
#pragma unroll
    for (int j = 0; j < 32; j++) {
        int o = o0 + j;
        float v = fmaf(acc[j], sc[o], bi[o]);
        out[((b << 7) + o) * 4096 + hw0 + lane] = v > 0.0f ? v : 0.0f;
    }
}

// ---------------- k3: om = conv3x3(offset, W_om) + b_om   Cin=128 Cout=216 (padded 224)
// block: one 8x8 pixel tile; 4 waves x 56 out channels; halo tile 10x10 in LDS
__global__ __launch_bounds__(256) void k_om(const float* __restrict__ off,
        const float* __restrict__ Wt, const float* __restrict__ bom,
        float* __restrict__ om) {
    __shared__ float X[128 * 100];
    const int t = threadIdx.x;
    const int bid = blockIdx.x;             // 512 = 8 b * 64 tiles
    const int b = bid >> 6;
    const int y0 = ((bid >> 3) & 7) << 3;
    const int x0 = (bid & 7) << 3;
    for (int i = t; i < 128 * 100; i += 256) {
        int c = i / 100, j = i - c * 100;
        int sy = j / 10, sx = j - sy * 10;
        int gy = y0 + sy - 1, gx = x0 + sx - 1;
        float v = 0.0f;
        if (gy >= 0 && gy < 64 && gx >= 0 && gx < 64)
            v = off[((b << 7) + c) * 4096 + (gy << 6) + gx];
        X[i] = v;
    }
    __syncthreads();
    const int lane = t & 63;
    const int wid = __builtin_amdgcn_readfirstlane(t >> 6);
    const int o0 = wid * 56;                // 56*4 waves = 224 (cols 216..223 are zero pad)
    const int ly = lane >> 3, lx = lane & 7;
    float acc[56];
#pragma unroll
    for (int j = 0; j < 56; j++) acc[j] = 0.0f;
    for (int c = 0; c < 128; c++) {
#pragma unroll
        for (int tap = 0; tap < 9; tap++) {
            int dy = tap / 3, dx = tap - dy * 3;      // 0..2
            float xv = X[c * 100 + (ly + dy) * 10 + (lx + dx)];
            const float* wr = (const float*)__builtin_assume_aligned(
                Wt + (c * 9 + tap) * 224 + o0, 16);
#pragma unroll
            for (int j = 0; j < 56; j++) acc[j] = fmaf(xv, wr[j], acc[j]);
        }
    }
    const int hw = ((y0 + ly) << 6) + x0 + lx;
#pragma unroll
    for (int j = 0; j < 56; j++) {
        int o = o0 + j;
        if (o < 216)
            om[(b * 216 + o) * 4096 + hw] = acc[j] + bom[o];
    }
}

// ---------------- k4: DCNv2 sample + matmul + relu -> feat_align  (Cout=64)
// block: 64 px; 4 waves each own 2 deformable groups; LDS reduce across waves
__global__ __launch_bounds__(256) void k_dcn(const float* __restrict__ fs,
        const float* __restrict__ om, const float* __restrict__ Wt,
        const float* __restrict__ bd, float* __restrict__ outp) {
    __shared__ float R[4 * 4096];
    const int t = threadIdx.x;
    const int lane = t & 63;
    const int wid = __builtin_amdgcn_readfirstlane(t >> 6);
    const int pb = blockIdx.x * 64;         // 512 blocks
    const int b = pb >> 12;
    const int hw0 = pb & 4095;
    const int h = hw0 >> 6;                 // uniform (one row per block)
    const int hw = hw0 + lane;
    const float fh = (float)h, fw = (float)lane;
    float acc[64];
#pragma unroll
    for (int j = 0; j < 64; j++) acc[j] = 0.0f;
    for (int gi = 0; gi < 2; gi++) {
        const int g = wid * 2 + gi;
#pragma unroll 1
        for (int k = 0; k < 9; k++) {
            const int ch = g * 9 + k;
            float oy = om[(b * 216 + ch) * 4096 + hw];
            float ox = om[(b * 216 + 72 + ch) * 4096 + hw];
            float mm = om[(b * 216 + 144 + ch) * 4096 + hw];
            mm = 1.0f / (1.0f + __expf(-mm));
            float py = fh + (float)(k / 3 - 1) + oy;
            float px = fw + (float)(k - (k / 3) * 3 - 1) + ox;
            float y0f = floorf(py), x0f = floorf(px);
            float ty = py - y0f, tx = px - x0f;
            int y0i = (int)y0f, x0i = (int)x0f;
            int y1i = y0i + 1, x1i = x0i + 1;
            bool vy0 = (y0i >= 0) && (y0i < 64);
            bool vy1 = (y1i >= 0) && (y1i < 64);
            bool vx0 = (x0i >= 0) && (x0i < 64);
            bool vx1 = (x1i >= 0) && (x1i < 64);
            float w00 = (vy0 && vx0) ? (1.0f - ty) * (1.0f - tx) * mm : 0.0f;
            float w01 = (vy0 && vx1) ? (1.0f - ty) * tx * mm : 0.0f;
            float w10 = (vy1 && vx0) ? ty * (1.0f - tx) * mm : 0.0f;
            float w11 = (vy1 && vx1) ? ty * tx * mm : 0.0f;
            int yc0 = y0i < 0 ? 0 : (y0i > 63 ? 63 : y0i);
            int yc1 = y1i < 0 ? 0 : (y1i > 63 ? 63 : y1i);
            int xc0 = x0i < 0 ? 0 : (x0i > 63 ? 63 : x0i);
            int xc1 = x1i < 0 ? 0 : (x1i > 63 ? 63 : x1i);
            // feat_up[y][x] = feat_s[y>>1][x>>1]
            int s00 = (yc0 >> 1) * 32 + (xc0 >> 1);
            int s01 = (yc0 >> 1) * 32 + (xc1 >> 1);
            int s10 = (yc1 >> 1) * 32 + (xc0 >> 1);
            int s11 = (yc1 >> 1) * 32 + (xc1 >> 1);
            const int base = (((b << 7) + (g << 4)) << 10);
#pragma unroll 4
            for (int c = 0; c < 16; c++) {
                const float* f = fs + base + (c << 10);
                float v = w00 * f[s00] + w01 * f[s01] + w10 * f[s10] + w11 * f[s11];
                const float* wr = (const float*)__builtin_assume_aligned(
                    Wt + (((g << 4) + c) * 9 + k) * 64, 16);
#pragma unroll
                for (int j = 0; j < 64; j++) acc[j] = fmaf(v, wr[j], acc[j]);
            }
        }
    }
#pragma unroll
    for (int j = 0; j < 64; j++) R[wid * 4096 + (j << 6) + lane] = acc[j];
    __syncthreads();
    for (int i = t; i < 4096; i += 256) {
        float v = R[i] + R[4096 + i] + R[8192 + i] + R[12288 + i];
        int o = i >> 6, px = i & 63;
        v += bd[o];
        v = v > 0.0f ? v : 0.0f;
        outp[((b << 6) + o) * 4096 + hw0 + px] = v;
    }
}

// ---------------- k5: feat = relu(W_cat . feat_align * s + b) + feat_arm   Cin=64 Cout=128
__global__ __launch_bounds__(256) void k_cat(const float* __restrict__ al,
        const float* __restrict__ Wt, const float* __restrict__ sc,
        const float* __restrict__ bi, const float* __restrict__ arm,
        float* __restrict__ out) {
    __shared__ float X[64 * 64];
    const int t = threadIdx.x;
    const int pb = blockIdx.x * 64;
    const int b = pb >> 12;
    const int hw0 = pb & 4095;
    for (int i = t; i < 64 * 64; i += 256) {
        int c = i >> 6, px = i & 63;
        X[i] = al[((b << 6) + c) * 4096 + hw0 + px];
    }
    __syncthreads();
    const int lane = t & 63;
    const int wid = __builtin_amdgcn_readfirstlane(t >> 6);
    const int o0 = wid * 32;
    float acc[32];
#pragma unroll
    for (int j = 0; j < 32; j++) acc[j] = 0.0f;
    for (int c = 0; c < 64; c++) {
        float xv = X[(c << 6) + lane];
        const float* wr = (const float*)__builtin_assume_aligned(Wt + (c << 7) + o0, 16);
#pragma unroll
        for (int j = 0; j < 32; j++) acc[j] = fmaf(xv, wr[j], acc[j]);
    }
#pragma unroll
    for (int j = 0; j < 32; j++) {
        int o = o0 + j;
        float v = fmaf(acc[j], sc[o], bi[o]);
        v = v > 0.0f ? v : 0.0f;
        v += arm[((b << 7) + o) * 4096 + hw0 + lane];
        out[((b << 7) + o) * 4096 + hw0 + lane] = v;
    }
}

extern "C" void kernel_launch(void* const* d_in, const int* in_sizes, int n_in,
                              void* d_out, int out_size, void* d_ws, size_t ws_size,
                              hipStream_t stream) {
    const float* feat_l = (const float*)d_in[0];   // 8*128*64*64
    const float* feat_s = (const float*)d_in[1];   // 8*128*32*32
    const float* W_fsm  = (const float*)d_in[2];   // 128*128
    const float* s_fsm  = (const float*)d_in[3];
    const float* b_fsm  = (const float*)d_in[4];
    const float* W_off  = (const float*)d_in[5];   // 128*256
    const float* s_off  = (const float*)d_in[6];
    const float* b_off  = (const float*)d_in[7];
    const float* W_om   = (const float*)d_in[8];   // 216*128*9
    const float* b_om   = (const float*)d_in[9];
    const float* W_dcn  = (const float*)d_in[10];  // 64*128*9
    const float* b_dcn  = (const float*)d_in[11];
    const float* W_cat  = (const float*)d_in[12];  // 128*64
    const float* s_cat  = (const float*)d_in[13];
    const float* b_cat  = (const float*)d_in[14];

    float* feat     = (float*)d_out;               // output 0: 4,194,304
    float* feat_arm = feat + 4194304;              // output 1: 4,194,304

    float* ws = (float*)d_ws;
    float* offset_ws = ws;                         // 4,194,304
    float* om_ws     = offset_ws + 4194304;        // 7,077,888
    float* align_ws  = om_ws + 7077888;            // 2,097,152
    float* wfsm_t    = align_ws + 2097152;         // 16,384   [c][o] 128x128
    float* woff_t    = wfsm_t + 16384;             // 32,768   [c][o] 256x128
    float* wom_t     = woff_t + 32768;             // 258,048  [ct][o] 1152x224 (pad)
    float* wdcn_t    = wom_t + 258048;             // 73,728   [ct][o] 1152x64
    float* wcat_t    = wdcn_t + 73728;             // 8,192    [c][o] 64x128

    k_transpose<<<64, 256, 0, stream>>>(W_fsm, wfsm_t, 128, 128, 128);
    k_transpose<<<128, 256, 0, stream>>>(W_off, woff_t, 128, 256, 128);
    k_transpose<<<1008, 256, 0, stream>>>(W_om, wom_t, 216, 1152, 224);
    k_transpose<<<288, 256, 0, stream>>>(W_dcn, wdcn_t, 64, 1152, 64);
    k_transpose<<<32, 256, 0, stream>>>(W_cat, wcat_t, 128, 64, 128);

    k_fsm<<<512, 256, 0, stream>>>(feat_l, wfsm_t, s_fsm, b_fsm, feat_arm);
    k_off<<<512, 256, 0, stream>>>(feat_arm, feat_s, woff_t, s_off, b_off, offset_ws);
    k_om<<<512, 256, 0, stream>>>(offset_ws, wom_t, b_om, om_ws);
    k_dcn<<<512, 256, 0, stream>>>(feat_s, om_ws, wdcn_t, b_dcn, align_ws);
    k_cat<<<512, 256, 0, stream>>>(align_ws, wcat_t, s_cat, b_cat, feat_arm, feat);
}

// Round 2
// 394.991 us; speedup vs baseline: 1.7704x; 1.7704x over previous
//
#include <hip/hip_runtime.h>
#include <hip/hip_bf16.h>

// Problem constants: B=8, C=128, H=W=64, G=8, K=9, Cg=16, Cd=64
// Pixel layout NCHW, HW = 4096.

typedef __attribute__((ext_vector_type(8))) short short8;
typedef __attribute__((ext_vector_type(4))) float f32x4;

static __device__ __forceinline__ unsigned short f2bf(float x) {
    union { float f; unsigned int u; } v; v.f = x;
    unsigned int r = (v.u + 0x7FFF + ((v.u >> 16) & 1)) >> 16;  // RNE
    return (unsigned short)r;
}

// ---------------- generic weight transpose: dst[ct*stride + o] = src[o*CT + ct]
__global__ __launch_bounds__(256) void k_transpose(const float* __restrict__ src,
        float* __restrict__ dst, int O, int CT, int stride) {
    int i = blockIdx.x * 256 + threadIdx.x;
    if (i >= CT * stride) return;
    int ct = i / stride;
    int o = i - ct * stride;
    dst[i] = (o < O) ? src[o * CT + ct] : 0.0f;
}

// ---------------- pack W_om into MFMA B-fragment order, bf16
// Wb2[(((tap*4+cc)*14+nt)*64 + lane)*8 + j] = bf16(W_om[o][c][tap]), o=nt*16+(lane&15),
// c = cc*32 + (lane>>4)*8 + j; zero-pad o>=216.
__global__ __launch_bounds__(256) void k_prepw(const float* __restrict__ Wom,
        unsigned short* __restrict__ Wb2) {
    int idx = blockIdx.x * 256 + threadIdx.x;
    if (idx >= 9 * 4 * 14 * 64) return;
    int lane = idx & 63;
    int t2 = idx >> 6;
    int nt = t2 % 14;
    int cc = (t2 / 14) % 4;
    int tap = t2 / 56;
    int o = nt * 16 + (lane & 15);
    int c0 = cc * 32 + (lane >> 4) * 8;
    unsigned short tmp[8];
#pragma unroll
    for (int j = 0; j < 8; j++) {
        float v = (o < 216) ? Wom[(o * 128 + (c0 + j)) * 9 + tap] : 0.0f;
        tmp[j] = f2bf(v);
    }
    ((uint4*)Wb2)[idx] = *(const uint4*)tmp;
}

// ---------------- k1: feat_arm = relu(W_fsm . feat_l * s + b)   Cin=128 Cout=128
__global__ __launch_bounds__(256) void k_fsm(const float* __restrict__ x,
        const float* __restrict__ Wt, const float* __restrict__ sc,
        const float* __restrict__ bi, float* __restrict__ out) {
    __shared__ float X[128 * 64];
    const int t = threadIdx.x;
    const int pb = blockIdx.x * 64;        // 512 blocks x 64 px
    const int b = pb >> 12;
    const int hw0 = pb & 4095;
    for (int i = t; i < 128 * 64; i += 256) {
        int c = i >> 6, px = i & 63;
        X[i] = x[((b << 7) + c) * 4096 + hw0 + px];
    }
    __syncthreads();
    const int lane = t & 63;
    const int wid = __builtin_amdgcn_readfirstlane(t >> 6);
    const int o0 = wid * 32;
    float acc[32];
#pragma unroll
    for (int j = 0; j < 32; j++) acc[j] = 0.0f;
    for (int c = 0; c < 128; c++) {
        float xv = X[(c << 6) + lane];
        const float* wr = (const float*)__builtin_assume_aligned(Wt + (c << 7) + o0, 16);
#pragma unroll
        for (int j = 0; j < 32; j++) acc[j] = fmaf(xv, wr[j], acc[j]);
    }
#pragma unroll
    for (int j = 0; j < 32; j++) {
        int o = o0 + j;
        float v = fmaf(acc[j], sc[o], bi[o]);
        out[((b << 7) + o) * 4096 + hw0 + lane] = v > 0.0f ? v : 0.0f;
    }
}

// ---------------- k2: offset = relu(W_off . concat(feat_arm, 2*feat_up) * s + b)
// Cin=256 Cout=128 -> writes bf16 PIXEL-MAJOR offT[(b*4096+hw)*128 + c]
__global__ __launch_bounds__(256) void k_off(const float* __restrict__ arm,
        const float* __restrict__ fs, const float* __restrict__ Wt,
        const float* __restrict__ sc, const float* __restrict__ bi,
        unsigned short* __restrict__ offT) {
    __shared__ float X[256 * 64];
    const int t = threadIdx.x;
    const int pb = blockIdx.x * 64;
    const int b = pb >> 12;
    const int hw0 = pb & 4095;
    const int h = hw0 >> 6;                 // uniform: block covers one row
    for (int i = t; i < 256 * 64; i += 256) {
        int c = i >> 6, px = i & 63;
        float v;
        if (c < 128) {
            v = arm[((b << 7) + c) * 4096 + hw0 + px];
        } else {
            int cc = c - 128;
            v = 2.0f * fs[((b << 7) + cc) * 1024 + ((h >> 1) << 5) + (px >> 1)];
        }
        X[i] = v;
    }
    __syncthreads();
    const int lane = t & 63;
    const int wid = __builtin_amdgcn_readfirstlane(t >> 6);
    const int o0 = wid * 32;
    float acc[32];
#pragma unroll
    for (int j = 0; j < 32; j++) acc[j] = 0.0f;
    for (int c = 0; c < 256; c++) {
        float xv = X[(c << 6) + lane];
        const float* wr = (const float*)__builtin_assume_aligned(Wt + (c << 7) + o0, 16);
#pragma unroll
        for (int j = 0; j < 32; j++) acc[j] = fmaf(xv, wr[j], acc[j]);
    }
    __syncthreads();                        // done reading X; reuse as bf16 epi buffer
    unsigned short* E = (unsigned short*)X; // [64 px][128 c]
#pragma unroll
    for (int j = 0; j < 32; j++) {
        int o = o0 + j;
        float v = fmaf(acc[j], sc[o], bi[o]);
        E[lane * 128 + o] = f2bf(v > 0.0f ? v : 0.0f);
    }
    __syncthreads();
    const uint2* Eu = (const uint2*)E;      // 32 uint2 per px row
    uint2* Ou = (uint2*)offT;
    for (int i = t; i < 64 * 32; i += 256) {
        int px = i >> 5;
        Ou[((b << 12) + hw0 + px) * 32 + (i & 31)] = Eu[i];
    }
}

// ---------------- k3: om = conv3x3(offset, W_om) + b_om   via bf16 MFMA implicit GEMM
// block: 8x8 px tile, 4 waves x 16 px; N=224 (14 tiles of 16); K = 9 taps x 128 c
__global__ __launch_bounds__(256) void k_om(const unsigned short* __restrict__ offT,
        const unsigned short* __restrict__ Wb2, const float* __restrict__ bom,
        float* __restrict__ om) {
    __shared__ float smem[64 * 229];        // 58624 B; overlaid halo stage (bf16)
    unsigned short* st = (unsigned short*)smem;  // [100 px][stride 136] bf16
    const int t = threadIdx.x;
    const int bid = blockIdx.x;             // 512 = 8 b * 64 tiles
    const int b = bid >> 6;
    const int y0 = ((bid >> 3) & 7) << 3;
    const int x0 = (bid & 7) << 3;
    // stage halo: 100 px x 128 c bf16, 16 uint4 per px row
    for (int i = t; i < 100 * 16; i += 256) {
        int pix = i >> 4, cg = i & 15;
        int sy = pix / 10, sx = pix - sy * 10;
        int gy = y0 + sy - 1, gx = x0 + sx - 1;
        uint4 v = make_uint4(0, 0, 0, 0);
        if (gy >= 0 && gy < 64 && gx >= 0 && gx < 64)
            v = ((const uint4*)offT)[((b << 12) + (gy << 6) + gx) * 16 + cg];
        ((uint4*)(st + pix * 136))[cg] = v;
    }
    __syncthreads();
    const int lane = t & 63;
    const int wid = __builtin_amdgcn_readfirstlane(t >> 6);
    const int m = lane & 15;
    const int ko = lane >> 4;
    const int p = wid * 16 + m;             // px within 8x8 tile
    const int ty = p >> 3, tx = p & 7;
    f32x4 acc[14];
#pragma unroll
    for (int nt = 0; nt < 14; nt++) acc[nt] = (f32x4){0.f, 0.f, 0.f, 0.f};
    for (int tap = 0; tap < 9; tap++) {
        const int dy = tap / 3, dx = tap - (tap / 3) * 3;
        const int pixL = (ty + dy) * 10 + (tx + dx);
#pragma unroll
        for (int cc = 0; cc < 4; cc++) {
            short8 av = *(const short8*)(st + pixL * 136 + cc * 32 + ko * 8);
            const uint4* wb = (const uint4*)Wb2 + ((tap * 4 + cc) * 14) * 64 + lane;
#pragma unroll
            for (int nt = 0; nt < 14; nt++) {
                uint4 bu = wb[nt * 64];
                short8 bv = *(const short8*)&bu;
                acc[nt] = __builtin_amdgcn_mfma_f32_16x16x32_bf16(av, bv, acc[nt], 0, 0, 0);
            }
        }
    }
    __syncthreads();                        // done reading stage; reuse as f32 epi
#pragma unroll
    for (int nt = 0; nt < 14; nt++) {
#pragma unroll
        for (int r = 0; r < 4; r++) {
            int mm = ko * 4 + r;            // D row = (lane>>4)*4 + r
            int pp = wid * 16 + mm;
            int o = nt * 16 + m;            // D col = lane&15
            smem[pp * 229 + o] = acc[nt][r];
        }
    }
    __syncthreads();
    for (int i = t; i < 216 * 64; i += 256) {
        int o = i >> 6, pp = i & 63;
        float v = smem[pp * 229 + o] + bom[o];
        om[(b * 216 + o) * 4096 + ((y0 + (pp >> 3)) << 6) + x0 + (pp & 7)] = v;
    }
}

// ---------------- k4: DCNv2 sample + matmul + relu -> feat_align  (Cout=64)
__global__ __launch_bounds__(256) void k_dcn(const float* __restrict__ fs,
        const float* __restrict__ om, const float* __restrict__ Wt,
        const float* __restrict__ bd, float* __restrict__ outp) {
    __shared__ float R[4 * 4096];
    const int t = threadIdx.x;
    const int lane = t & 63;
    const int wid = __builtin_amdgcn_readfirstlane(t >> 6);
    const int pb = blockIdx.x * 64;         // 512 blocks
    const int b = pb >> 12;
    const int hw0 = pb & 4095;
    const int h = hw0 >> 6;                 // uniform (one row per block)
    const int hw = hw0 + lane;
    const float fh = (float)h, fw = (float)lane;
    float acc[64];
#pragma unroll
    for (int j = 0; j < 64; j++) acc[j] = 0.0f;
    for (int gi = 0; gi < 2; gi++) {
        const int g = wid * 2 + gi;
#pragma unroll 1
        for (int k = 0; k < 9; k++) {
            const int ch = g * 9 + k;
            float oy = om[(b * 216 + ch) * 4096 + hw];
            float ox = om[(b * 216 + 72 + ch) * 4096 + hw];
            float mm = om[(b * 216 + 144 + ch) * 4096 + hw];
            mm = 1.0f / (1.0f + __expf(-mm));
            float py = fh + (float)(k / 3 - 1) + oy;
            float px = fw + (float)(k - (k / 3) * 3 - 1) + ox;
            float y0f = floorf(py), x0f = floorf(px);
            float ty = py - y0f, tx = px - x0f;
            int y0i = (int)y0f, x0i = (int)x0f;
            int y1i = y0i + 1, x1i = x0i + 1;
            bool vy0 = (y0i >= 0) && (y0i < 64);
            bool vy1 = (y1i >= 0) && (y1i < 64);
            bool vx0 = (x0i >= 0) && (x0i < 64);
            bool vx1 = (x1i >= 0) && (x1i < 64);
            float w00 = (vy0 && vx0) ? (1.0f - ty) * (1.0f - tx) * mm : 0.0f;
            float w01 = (vy0 && vx1) ? (1.0f - ty) * tx * mm : 0.0f;
            float w10 = (vy1 && vx0) ? ty * (1.0f - tx) * mm : 0.0f;
            float w11 = (vy1 && vx1) ? ty * tx * mm : 0.0f;
            int yc0 = y0i < 0 ? 0 : (y0i > 63 ? 63 : y0i);
            int yc1 = y1i < 0 ? 0 : (y1i > 63 ? 63 : y1i);
            int xc0 = x0i < 0 ? 0 : (x0i > 63 ? 63 : x0i);
            int xc1 = x1i < 0 ? 0 : (x1i > 63 ? 63 : x1i);
            int s00 = (yc0 >> 1) * 32 + (xc0 >> 1);
            int s01 = (yc0 >> 1) * 32 + (xc1 >> 1);
            int s10 = (yc1 >> 1) * 32 + (xc0 >> 1);
            int s11 = (yc1 >> 1) * 32 + (xc1 >> 1);
            const int base = (((b << 7) + (g << 4)) << 10);
#pragma unroll 4
            for (int c = 0; c < 16; c++) {
                const float* f = fs + base + (c << 10);
                float v = w00 * f[s00] + w01 * f[s01] + w10 * f[s10] + w11 * f[s11];
                const float* wr = (const float*)__builtin_assume_aligned(
                    Wt + (((g << 4) + c) * 9 + k) * 64, 16);
#pragma unroll
                for (int j = 0; j < 64; j++) acc[j] = fmaf(v, wr[j], acc[j]);
            }
        }
    }
#pragma unroll
    for (int j = 0; j < 64; j++) R[wid * 4096 + (j << 6) + lane] = acc[j];
    __syncthreads();
    for (int i = t; i < 4096; i += 256) {
        float v = R[i] + R[4096 + i] + R[8192 + i] + R[12288 + i];
        int o = i >> 6, px = i & 63;
        v += bd[o];
        v = v > 0.0f ? v : 0.0f;
        outp[((b << 6) + o) * 4096 + hw0 + px] = v;
    }
}

// ---------------- k5: feat = relu(W_cat . feat_align * s + b) + feat_arm   Cin=64 Cout=128
__global__ __launch_bounds__(256) void k_cat(const float* __restrict__ al,
        const float* __restrict__ Wt, const float* __restrict__ sc,
        const float* __restrict__ bi, const float* __restrict__ arm,
        float* __restrict__ out) {
    __shared__ float X[64 * 64];
    const int t = threadIdx.x;
    const int pb = blockIdx.x * 64;
    const int b = pb >> 12;
    const int hw0 = pb & 4095;
    for (int i = t; i < 64 * 64; i += 256) {
        int c = i >> 6, px = i & 63;
        X[i] = al[((b << 6) + c) * 4096 + hw0 + px];
    }
    __syncthreads();
    const int lane = t & 63;
    const int wid = __builtin_amdgcn_readfirstlane(t >> 6);
    const int o0 = wid * 32;
    float acc[32];
#pragma unroll
    for (int j = 0; j < 32; j++) acc[j] = 0.0f;
    for (int c = 0; c < 64; c++) {
        float xv = X[(c << 6) + lane];
        const float* wr = (const float*)__builtin_assume_aligned(Wt + (c << 7) + o0, 16);
#pragma unroll
        for (int j = 0; j < 32; j++) acc[j] = fmaf(xv, wr[j], acc[j]);
    }
#pragma unroll
    for (int j = 0; j < 32; j++) {
        int o = o0 + j;
        float v = fmaf(acc[j], sc[o], bi[o]);
        v = v > 0.0f ? v : 0.0f;
        v += arm[((b << 7) + o) * 4096 + hw0 + lane];
        out[((b << 7) + o) * 4096 + hw0 + lane] = v;
    }
}

extern "C" void kernel_launch(void* const* d_in, const int* in_sizes, int n_in,
                              void* d_out, int out_size, void* d_ws, size_t ws_size,
                              hipStream_t stream) {
    const float* feat_l = (const float*)d_in[0];   // 8*128*64*64
    const float* feat_s = (const float*)d_in[1];   // 8*128*32*32
    const float* W_fsm  = (const float*)d_in[2];   // 128*128
    const float* s_fsm  = (const float*)d_in[3];
    const float* b_fsm  = (const float*)d_in[4];
    const float* W_off  = (const float*)d_in[5];   // 128*256
    const float* s_off  = (const float*)d_in[6];
    const float* b_off  = (const float*)d_in[7];
    const float* W_om   = (const float*)d_in[8];   // 216*128*9
    const float* b_om   = (const float*)d_in[9];
    const float* W_dcn  = (const float*)d_in[10];  // 64*128*9
    const float* b_dcn  = (const float*)d_in[11];
    const float* W_cat  = (const float*)d_in[12];  // 128*64
    const float* s_cat  = (const float*)d_in[13];
    const float* b_cat  = (const float*)d_in[14];

    float* feat     = (float*)d_out;               // output 0: 4,194,304
    float* feat_arm = feat + 4194304;              // output 1: 4,194,304

    float* ws = (float*)d_ws;
    unsigned short* offT = (unsigned short*)ws;    // 4,194,304 ushort = 2,097,152 f
    float* om_ws     = ws + 2097152;               // 7,077,888
    float* align_ws  = om_ws + 7077888;            // 2,097,152
    float* wfsm_t    = align_ws + 2097152;         // 16,384   [c][o] 128x128
    float* woff_t    = wfsm_t + 16384;             // 32,768   [c][o] 256x128
    unsigned short* wb2 = (unsigned short*)(woff_t + 32768);  // 516,096 ushort = 258,048 f
    float* wdcn_t    = woff_t + 32768 + 258048;    // 73,728   [ct][o] 1152x64
    float* wcat_t    = wdcn_t + 73728;             // 8,192    [c][o] 64x128

    k_transpose<<<64, 256, 0, stream>>>(W_fsm, wfsm_t, 128, 128, 128);
    k_transpose<<<128, 256, 0, stream>>>(W_off, woff_t, 128, 256, 128);
    k_prepw<<<126, 256, 0, stream>>>(W_om, wb2);
    k_transpose<<<288, 256, 0, stream>>>(W_dcn, wdcn_t, 64, 1152, 64);
    k_transpose<<<32, 256, 0, stream>>>(W_cat, wcat_t, 128, 64, 128);

    k_fsm<<<512, 256, 0, stream>>>(feat_l, wfsm_t, s_fsm, b_fsm, feat_arm);
    k_off<<<512, 256, 0, stream>>>(feat_arm, feat_s, woff_t, s_off, b_off, offT);
    k_om<<<512, 256, 0, stream>>>(offT, wb2, b_om, om_ws);
    k_dcn<<<512, 256, 0, stream>>>(feat_s, om_ws, wdcn_t, b_dcn, align_ws);
    k_cat<<<512, 256, 0, stream>>>(align_ws, wcat_t, s_cat, b_cat, feat_arm, feat);
}

// Round 3
// 253.089 us; speedup vs baseline: 2.7631x; 1.5607x over previous
//
#include <hip/hip_runtime.h>

// B=8, C=128, H=W=64, G=8, K=9, Cg=16, Cd=64. NCHW, HW=4096.
// MFMA conventions (verified in-problem, round 2):
//   A-frag: lane&15 = m, k-octet = (lane>>4)*8 + j
//   B-frag: lane&15 = n, k-octet = (lane>>4)*8 + j
//   C/D:    col = lane&15 (n), row = (lane>>4)*4 + r (m)

typedef __attribute__((ext_vector_type(8))) short short8;
typedef __attribute__((ext_vector_type(4))) float f32x4;

static __device__ __forceinline__ unsigned short f2bf(float x) {
    union { float f; unsigned int u; } v; v.f = x;
    return (unsigned short)((v.u + 0x7FFF + ((v.u >> 16) & 1)) >> 16);  // RNE
}
static __device__ __forceinline__ float bflo(unsigned int u) {
    union { unsigned int u; float f; } v; v.u = u << 16; return v.f;
}
static __device__ __forceinline__ float bfhi(unsigned int u) {
    union { unsigned int u; float f; } v; v.u = u & 0xFFFF0000u; return v.f;
}

// ---------------- feat_s -> pixel-major bf16 fsT[(b*1024+px)*128 + c]
__global__ __launch_bounds__(256) void k_prepfs(const float* __restrict__ fs,
        uint4* __restrict__ fsT4) {
    __shared__ unsigned short st[64 * 136];
    unsigned int* st32 = (unsigned int*)st;
    const int t = threadIdx.x;
    const int b = blockIdx.x >> 4;
    const int p0 = (blockIdx.x & 15) << 6;
    for (int i = t; i < 64 * 64; i += 256) {
        int c2 = i >> 6, px = i & 63;
        float v0 = fs[(((b << 7) + 2 * c2) << 10) + p0 + px];
        float v1 = fs[(((b << 7) + 2 * c2 + 1) << 10) + p0 + px];
        st32[px * 68 + c2] = (unsigned int)f2bf(v0) | ((unsigned int)f2bf(v1) << 16);
    }
    __syncthreads();
    for (int i = t; i < 64 * 16; i += 256) {
        int px = i >> 4, q = i & 15;
        fsT4[(((b << 10) + p0 + px) << 4) + q] = ((const uint4*)(st + px * 136))[q];
    }
}

// ---------------- generic B-frag pack: dst[(kk*NT+nt)*64+lane] (uint4 units)
// o = nt*16+(lane&15), k = kk*32+(lane>>4)*8+j, src = W[o*K+k], x2 for k>=scaleFrom
__global__ __launch_bounds__(256) void k_pack(const float* __restrict__ W,
        unsigned short* __restrict__ dst, int K, int NT, int scaleFrom, int total) {
    int idx = blockIdx.x * 256 + threadIdx.x;
    if (idx >= total) return;
    int lane = idx & 63;
    int r = idx >> 6;
    int nt = r % NT;
    int kk = r / NT;
    int o = nt * 16 + (lane & 15);
    int k0 = kk * 32 + (lane >> 4) * 8;
    unsigned short tmp[8];
#pragma unroll
    for (int j = 0; j < 8; j++) {
        int k = k0 + j;
        float f = W[o * K + k];
        if (k >= scaleFrom) f *= 2.0f;
        tmp[j] = f2bf(f);
    }
    ((uint4*)dst)[idx] = *(const uint4*)tmp;
}

// ---------------- W_dcn pack: K ordering k = (g*9+tap)*16 + c, N=64 (NT=4)
__global__ __launch_bounds__(256) void k_packdcn(const float* __restrict__ Wd,
        unsigned short* __restrict__ dst) {
    int idx = blockIdx.x * 256 + threadIdx.x;
    if (idx >= 36 * 4 * 64) return;
    int lane = idx & 63;
    int r = idx >> 6;
    int nt = r & 3;
    int kk = r >> 2;
    int o = nt * 16 + (lane & 15);
    int k0 = kk * 32 + (lane >> 4) * 8;
    unsigned short tmp[8];
#pragma unroll
    for (int j = 0; j < 8; j++) {
        int k = k0 + j;
        int g = k / 144;
        int rem = k - g * 144;
        int tap = rem >> 4;
        int c = rem & 15;
        tmp[j] = f2bf(Wd[(o * 128 + g * 16 + c) * 9 + tap]);
    }
    ((uint4*)dst)[idx] = *(const uint4*)tmp;
}

// ---------------- W_om pack (round-2, verified): K = tap*128 + c, N=224
__global__ __launch_bounds__(256) void k_prepw(const float* __restrict__ Wom,
        unsigned short* __restrict__ Wb2) {
    int idx = blockIdx.x * 256 + threadIdx.x;
    if (idx >= 9 * 4 * 14 * 64) return;
    int lane = idx & 63;
    int t2 = idx >> 6;
    int nt = t2 % 14;
    int cc = (t2 / 14) % 4;
    int tap = t2 / 56;
    int o = nt * 16 + (lane & 15);
    int c0 = cc * 32 + (lane >> 4) * 8;
    unsigned short tmp[8];
#pragma unroll
    for (int j = 0; j < 8; j++) {
        float v = (o < 216) ? Wom[(o * 128 + (c0 + j)) * 9 + tap] : 0.0f;
        tmp[j] = f2bf(v);
    }
    ((uint4*)Wb2)[idx] = *(const uint4*)tmp;
}

// ---------------- k12: fused fsm GEMM (K=128) + off GEMM (K=256), per 64-px row block
__global__ __launch_bounds__(256) void k12(const float* __restrict__ feat_l,
        const uint4* __restrict__ fsT4,
        const unsigned short* __restrict__ wbf, const unsigned short* __restrict__ wbo,
        const float* __restrict__ s_fsm, const float* __restrict__ b_fsm,
        const float* __restrict__ s_off, const float* __restrict__ b_off,
        float* __restrict__ feat_arm, unsigned short* __restrict__ offT) {
    __shared__ unsigned short A1[64 * 136];   // 17408 B; overlaid E32 (64*67*4)
    __shared__ unsigned short A2[64 * 264];   // 33792 B: cols 0..127 arm, 128..255 up
    float* E32 = (float*)A1;
    const int t = threadIdx.x;
    const int b = blockIdx.x >> 6;
    const int h = blockIdx.x & 63;
    const int hw0 = h << 6;
    // stage A1: feat_l -> pixel-major bf16
    unsigned int* A1w = (unsigned int*)A1;
    for (int i = t; i < 64 * 64; i += 256) {
        int c2 = i >> 6, px = i & 63;
        float v0 = feat_l[(((b << 7) + 2 * c2) << 12) + hw0 + px];
        float v1 = feat_l[(((b << 7) + 2 * c2 + 1) << 12) + hw0 + px];
        A1w[px * 68 + c2] = (unsigned int)f2bf(v0) | ((unsigned int)f2bf(v1) << 16);
    }
    // stage A2 cols 128..255: feat_up (x2 folded into wbo)
    {
        const int h2 = h >> 1;
        for (int i = t; i < 32 * 16; i += 256) {
            int px2 = i >> 4, q = i & 15;
            uint4 v = fsT4[(((b << 10) + (h2 << 5) + px2) << 4) + q];
            ((uint4*)(A2 + (2 * px2) * 264 + 128))[q] = v;
            ((uint4*)(A2 + (2 * px2 + 1) * 264 + 128))[q] = v;
        }
    }
    __syncthreads();
    const int lane = t & 63;
    const int wid = __builtin_amdgcn_readfirstlane(t >> 6);
    const int m = lane & 15, ko = lane >> 4;
    // GEMM1: feat_arm
    f32x4 acc[8];
#pragma unroll
    for (int nt = 0; nt < 8; nt++) acc[nt] = (f32x4){0.f, 0.f, 0.f, 0.f};
#pragma unroll
    for (int kk = 0; kk < 4; kk++) {
        short8 av = *(const short8*)(A1 + (wid * 16 + m) * 136 + kk * 32 + ko * 8);
        const uint4* wb = (const uint4*)wbf + (kk * 8) * 64 + lane;
#pragma unroll
        for (int nt = 0; nt < 8; nt++) {
            uint4 bu = wb[nt * 64];
            acc[nt] = __builtin_amdgcn_mfma_f32_16x16x32_bf16(av, *(short8*)&bu, acc[nt], 0, 0, 0);
        }
    }
    // epilogue1: scale+bias+relu in place; bf16 copy into A2 cols 0..127
#pragma unroll
    for (int nt = 0; nt < 8; nt++) {
        int o = nt * 16 + m;
        float sc = s_fsm[o], bi = b_fsm[o];
#pragma unroll
        for (int r = 0; r < 4; r++) {
            float v = fmaf(acc[nt][r], sc, bi);
            v = v > 0.f ? v : 0.f;
            acc[nt][r] = v;
            A2[(wid * 16 + ko * 4 + r) * 264 + o] = f2bf(v);
        }
    }
    // feat_arm fp32 out via two LDS-transpose halves (E32 overlays A1)
#pragma unroll 1
    for (int half = 0; half < 2; half++) {
        __syncthreads();
#pragma unroll
        for (int nt2 = 0; nt2 < 4; nt2++) {
            int nt = half * 4 + nt2;
#pragma unroll
            for (int r = 0; r < 4; r++)
                E32[(wid * 16 + ko * 4 + r) * 67 + nt2 * 16 + m] = acc[nt][r];
        }
        __syncthreads();
        for (int i = t; i < 4096; i += 256) {
            int ol = i >> 6, pp = i & 63;
            feat_arm[(((b << 7) + half * 64 + ol) << 12) + hw0 + pp] = E32[pp * 67 + ol];
        }
    }
    __syncthreads();
    // GEMM2: offset (K=256)
    f32x4 acc2[8];
#pragma unroll
    for (int nt = 0; nt < 8; nt++) acc2[nt] = (f32x4){0.f, 0.f, 0.f, 0.f};
#pragma unroll
    for (int kk = 0; kk < 8; kk++) {
        short8 av = *(const short8*)(A2 + (wid * 16 + m) * 264 + kk * 32 + ko * 8);
        const uint4* wb = (const uint4*)wbo + (kk * 8) * 64 + lane;
#pragma unroll
        for (int nt = 0; nt < 8; nt++) {
            uint4 bu = wb[nt * 64];
            acc2[nt] = __builtin_amdgcn_mfma_f32_16x16x32_bf16(av, *(short8*)&bu, acc2[nt], 0, 0, 0);
        }
    }
    __syncthreads();
#pragma unroll
    for (int nt = 0; nt < 8; nt++) {
        int o = nt * 16 + m;
        float sc = s_off[o], bi = b_off[o];
#pragma unroll
        for (int r = 0; r < 4; r++) {
            float v = fmaf(acc2[nt][r], sc, bi);
            v = v > 0.f ? v : 0.f;
            A2[(wid * 16 + ko * 4 + r) * 264 + o] = f2bf(v);
        }
    }
    __syncthreads();
    for (int i = t; i < 64 * 16; i += 256) {
        int px = i >> 4, q = i & 15;
        ((uint4*)offT)[(((b << 12) + hw0 + px) << 4) + q] = ((const uint4*)(A2 + px * 264))[q];
    }
}

// ---------------- k3: om = conv3x3(offset) + b_om  (round-2, verified)
__global__ __launch_bounds__(256) void k_om(const unsigned short* __restrict__ offT,
        const unsigned short* __restrict__ Wb2, const float* __restrict__ bom,
        float* __restrict__ om) {
    __shared__ float smem[64 * 229];
    unsigned short* st = (unsigned short*)smem;
    const int t = threadIdx.x;
    const int bid = blockIdx.x;
    const int b = bid >> 6;
    const int y0 = ((bid >> 3) & 7) << 3;
    const int x0 = (bid & 7) << 3;
    for (int i = t; i < 100 * 16; i += 256) {
        int pix = i >> 4, cg = i & 15;
        int sy = pix / 10, sx = pix - sy * 10;
        int gy = y0 + sy - 1, gx = x0 + sx - 1;
        uint4 v = make_uint4(0, 0, 0, 0);
        if (gy >= 0 && gy < 64 && gx >= 0 && gx < 64)
            v = ((const uint4*)offT)[((b << 12) + (gy << 6) + gx) * 16 + cg];
        ((uint4*)(st + pix * 136))[cg] = v;
    }
    __syncthreads();
    const int lane = t & 63;
    const int wid = __builtin_amdgcn_readfirstlane(t >> 6);
    const int m = lane & 15;
    const int ko = lane >> 4;
    const int p = wid * 16 + m;
    const int ty = p >> 3, tx = p & 7;
    f32x4 acc[14];
#pragma unroll
    for (int nt = 0; nt < 14; nt++) acc[nt] = (f32x4){0.f, 0.f, 0.f, 0.f};
    for (int tap = 0; tap < 9; tap++) {
        const int dy = tap / 3, dx = tap - (tap / 3) * 3;
        const int pixL = (ty + dy) * 10 + (tx + dx);
#pragma unroll
        for (int cc = 0; cc < 4; cc++) {
            short8 av = *(const short8*)(st + pixL * 136 + cc * 32 + ko * 8);
            const uint4* wb = (const uint4*)Wb2 + ((tap * 4 + cc) * 14) * 64 + lane;
#pragma unroll
            for (int nt = 0; nt < 14; nt++) {
                uint4 bu = wb[nt * 64];
                acc[nt] = __builtin_amdgcn_mfma_f32_16x16x32_bf16(av, *(short8*)&bu, acc[nt], 0, 0, 0);
            }
        }
    }
    __syncthreads();
#pragma unroll
    for (int nt = 0; nt < 14; nt++) {
#pragma unroll
        for (int r = 0; r < 4; r++) {
            int mm = ko * 4 + r;
            int pp = wid * 16 + mm;
            int o = nt * 16 + m;
            smem[pp * 229 + o] = acc[nt][r];
        }
    }
    __syncthreads();
    for (int i = t; i < 216 * 64; i += 256) {
        int o = i >> 6, pp = i & 63;
        float v = smem[pp * 229 + o] + bom[o];
        om[(b * 216 + o) * 4096 + ((y0 + (pp >> 3)) << 6) + x0 + (pp & 7)] = v;
    }
}

// ---------------- k45: fused DCNv2 (MFMA, K=1152 split across 2 wave-sets) + cat GEMM
__global__ __launch_bounds__(512) void k45(const uint4* __restrict__ fsT4,
        const float* __restrict__ om, const unsigned short* __restrict__ wbd,
        const float* __restrict__ bd, const unsigned short* __restrict__ wbc,
        const float* __restrict__ s_cat, const float* __restrict__ b_cat,
        const float* __restrict__ feat_arm, float* __restrict__ feat) {
    __shared__ float R1[64 * 67];            // 17152 B: reduce buf, then epilogue
    __shared__ unsigned short A3[64 * 72];   // 9216 B: align bf16 pixel-major
    const int t = threadIdx.x;
    const int lane = t & 63;
    const int wid = __builtin_amdgcn_readfirstlane(t >> 6);  // 0..7
    const int mt = wid & 3, kh = wid >> 2;
    const int b = blockIdx.x >> 6;
    const int h = blockIdx.x & 63;
    const int hw0 = h << 6;
    const int m = lane & 15, ko = lane >> 4;
    const int px = mt * 16 + m;
    const int hw = hw0 + px;
    const float fh = (float)h, fw = (float)px;
    const int ombase = (b * 216) * 4096 + hw;
    const int pb_ = b << 10;
    f32x4 acc[4];
#pragma unroll
    for (int nt = 0; nt < 4; nt++) acc[nt] = (f32x4){0.f, 0.f, 0.f, 0.f};
#pragma unroll 1
    for (int kk = 0; kk < 18; kk++) {
        int k0 = kh * 576 + kk * 32 + ko * 8;
        int g = k0 / 144;
        int rem = k0 - g * 144;
        int tap = rem >> 4;
        int c0 = rem & 15;          // 0 or 8
        int ch = g * 9 + tap;
        float oy = om[ombase + ch * 4096];
        float ox = om[ombase + (72 + ch) * 4096];
        float mmv = om[ombase + (144 + ch) * 4096];
        mmv = 1.0f / (1.0f + __expf(-mmv));
        float py = fh + (float)(tap / 3 - 1) + oy;
        float pxx = fw + (float)(tap % 3 - 1) + ox;
        float y0f = floorf(py), x0f = floorf(pxx);
        float tyf = py - y0f, txf = pxx - x0f;
        int y0i = (int)y0f, x0i = (int)x0f;
        int y1i = y0i + 1, x1i = x0i + 1;
        bool vy0 = (y0i >= 0) && (y0i < 64);
        bool vy1 = (y1i >= 0) && (y1i < 64);
        bool vx0 = (x0i >= 0) && (x0i < 64);
        bool vx1 = (x1i >= 0) && (x1i < 64);
        float w00 = (vy0 && vx0) ? (1.0f - tyf) * (1.0f - txf) * mmv : 0.0f;
        float w01 = (vy0 && vx1) ? (1.0f - tyf) * txf * mmv : 0.0f;
        float w10 = (vy1 && vx0) ? tyf * (1.0f - txf) * mmv : 0.0f;
        float w11 = (vy1 && vx1) ? tyf * txf * mmv : 0.0f;
        int yc0 = y0i < 0 ? 0 : (y0i > 63 ? 63 : y0i);
        int yc1 = y1i < 0 ? 0 : (y1i > 63 ? 63 : y1i);
        int xc0 = x0i < 0 ? 0 : (x0i > 63 ? 63 : x0i);
        int xc1 = x1i < 0 ? 0 : (x1i > 63 ? 63 : x1i);
        int row0 = (yc0 >> 1) << 5, row1 = (yc1 >> 1) << 5;
        int ci = g * 2 + (c0 >> 3);
        uint4 A00 = fsT4[((pb_ + row0 + (xc0 >> 1)) << 4) + ci];
        uint4 A01 = fsT4[((pb_ + row0 + (xc1 >> 1)) << 4) + ci];
        uint4 A10 = fsT4[((pb_ + row1 + (xc0 >> 1)) << 4) + ci];
        uint4 A11 = fsT4[((pb_ + row1 + (xc1 >> 1)) << 4) + ci];
        union { short8 s; unsigned short u[8]; } av;
#define DOU(idx, comp) { \
        unsigned int q00 = A00.comp, q01 = A01.comp, q10 = A10.comp, q11 = A11.comp; \
        float vl = w00 * bflo(q00) + w01 * bflo(q01) + w10 * bflo(q10) + w11 * bflo(q11); \
        float vh = w00 * bfhi(q00) + w01 * bfhi(q01) + w10 * bfhi(q10) + w11 * bfhi(q11); \
        av.u[2 * idx] = f2bf(vl); av.u[2 * idx + 1] = f2bf(vh); }
        DOU(0, x) DOU(1, y) DOU(2, z) DOU(3, w)
#undef DOU
        const uint4* wb = (const uint4*)wbd + ((kh * 18 + kk) * 4) * 64 + lane;
#pragma unroll
        for (int nt = 0; nt < 4; nt++) {
            uint4 bu = wb[nt * 64];
            acc[nt] = __builtin_amdgcn_mfma_f32_16x16x32_bf16(av.s, *(short8*)&bu, acc[nt], 0, 0, 0);
        }
    }
    // reduce the two K-halves, add bias, relu, emit bf16 A for cat GEMM
    if (kh == 1) {
#pragma unroll
        for (int nt = 0; nt < 4; nt++)
#pragma unroll
            for (int r = 0; r < 4; r++)
                R1[(mt * 16 + ko * 4 + r) * 67 + nt * 16 + m] = acc[nt][r];
    }
    __syncthreads();
    if (kh == 0) {
#pragma unroll
        for (int nt = 0; nt < 4; nt++) {
            int o = nt * 16 + m;
            float bv = bd[o];
#pragma unroll
            for (int r = 0; r < 4; r++) {
                int prow = mt * 16 + ko * 4 + r;
                float v = acc[nt][r] + R1[prow * 67 + o] + bv;
                v = v > 0.f ? v : 0.f;
                A3[prow * 72 + o] = f2bf(v);
            }
        }
    }
    __syncthreads();
    // cat GEMM: K=64, N=128; wave (mt, nh=kh) covers N-tiles nh*4..nh*4+3
    f32x4 accc[4];
#pragma unroll
    for (int nt = 0; nt < 4; nt++) accc[nt] = (f32x4){0.f, 0.f, 0.f, 0.f};
#pragma unroll
    for (int kk2 = 0; kk2 < 2; kk2++) {
        short8 av = *(const short8*)(A3 + (mt * 16 + m) * 72 + kk2 * 32 + ko * 8);
        const uint4* wb = (const uint4*)wbc + (kk2 * 8 + kh * 4) * 64 + lane;
#pragma unroll
        for (int nt = 0; nt < 4; nt++) {
            uint4 bu = wb[nt * 64];
            accc[nt] = __builtin_amdgcn_mfma_f32_16x16x32_bf16(av, *(short8*)&bu, accc[nt], 0, 0, 0);
        }
    }
    // epilogue: relu(acc*s+b) + feat_arm, two halves through R1
#pragma unroll 1
    for (int half = 0; half < 2; half++) {
        __syncthreads();
        if (kh == half) {
#pragma unroll
            for (int nt = 0; nt < 4; nt++) {
                int ol = nt * 16 + m;
                int o = half * 64 + ol;
                float sc = s_cat[o], bi = b_cat[o];
#pragma unroll
                for (int r = 0; r < 4; r++) {
                    float v = fmaf(accc[nt][r], sc, bi);
                    v = v > 0.f ? v : 0.f;
                    R1[(mt * 16 + ko * 4 + r) * 67 + ol] = v;
                }
            }
        }
        __syncthreads();
        for (int i = t; i < 4096; i += 512) {
            int ol = i >> 6, pp = i & 63;
            int gidx = (((b << 7) + half * 64 + ol) << 12) + hw0 + pp;
            feat[gidx] = R1[pp * 67 + ol] + feat_arm[gidx];
        }
    }
}

extern "C" void kernel_launch(void* const* d_in, const int* in_sizes, int n_in,
                              void* d_out, int out_size, void* d_ws, size_t ws_size,
                              hipStream_t stream) {
    const float* feat_l = (const float*)d_in[0];
    const float* feat_s = (const float*)d_in[1];
    const float* W_fsm  = (const float*)d_in[2];
    const float* s_fsm  = (const float*)d_in[3];
    const float* b_fsm  = (const float*)d_in[4];
    const float* W_off  = (const float*)d_in[5];
    const float* s_off  = (const float*)d_in[6];
    const float* b_off  = (const float*)d_in[7];
    const float* W_om   = (const float*)d_in[8];
    const float* b_om   = (const float*)d_in[9];
    const float* W_dcn  = (const float*)d_in[10];
    const float* b_dcn  = (const float*)d_in[11];
    const float* W_cat  = (const float*)d_in[12];
    const float* s_cat  = (const float*)d_in[13];
    const float* b_cat  = (const float*)d_in[14];

    float* feat     = (float*)d_out;
    float* feat_arm = feat + 4194304;

    float* ws = (float*)d_ws;
    unsigned short* offT = (unsigned short*)ws;            // 2,097,152 f
    float* om_ws = ws + 2097152;                           // 7,077,888 f
    uint4* fsT4  = (uint4*)(ws + 9175040);                 //   524,288 f
    unsigned short* wb2   = (unsigned short*)(ws + 9699328);   // 129,024 f
    unsigned short* wbfsm = (unsigned short*)(ws + 9828352);   //   8,192 f
    unsigned short* wboff = (unsigned short*)(ws + 9836544);   //  16,384 f
    unsigned short* wbcat = (unsigned short*)(ws + 9852928);   //   4,096 f
    unsigned short* wbdcn = (unsigned short*)(ws + 9857024);   //  36,864 f

    k_prepfs<<<128, 256, 0, stream>>>(feat_s, fsT4);
    k_pack<<<8, 256, 0, stream>>>(W_fsm, wbfsm, 128, 8, 1 << 30, 2048);
    k_pack<<<16, 256, 0, stream>>>(W_off, wboff, 256, 8, 128, 4096);
    k_pack<<<4, 256, 0, stream>>>(W_cat, wbcat, 64, 8, 1 << 30, 1024);
    k_packdcn<<<36, 256, 0, stream>>>(W_dcn, wbdcn);
    k_prepw<<<126, 256, 0, stream>>>(W_om, wb2);

    k12<<<512, 256, 0, stream>>>(feat_l, fsT4, wbfsm, wboff,
                                 s_fsm, b_fsm, s_off, b_off, feat_arm, offT);
    k_om<<<512, 256, 0, stream>>>(offT, wb2, b_om, om_ws);
    k45<<<512, 512, 0, stream>>>(fsT4, om_ws, wbdcn, b_dcn, wbcat,
                                 s_cat, b_cat, feat_arm, feat);
}

// Round 4
// 244.142 us; speedup vs baseline: 2.8643x; 1.0367x over previous
//
#include <hip/hip_runtime.h>

// B=8, C=128, H=W=64, G=8, K=9, Cg=16, Cd=64. NCHW, HW=4096.
// MFMA conventions (verified in-problem, round 2):
//   A-frag: lane&15 = m, k-octet = (lane>>4)*8 + j
//   B-frag: lane&15 = n, k-octet = (lane>>4)*8 + j
//   C/D:    col = lane&15 (n), row = (lane>>4)*4 + r (m)

typedef __attribute__((ext_vector_type(8))) short short8;
typedef __attribute__((ext_vector_type(4))) float f32x4;

static __device__ __forceinline__ unsigned short f2bf(float x) {
    union { float f; unsigned int u; } v; v.f = x;
    return (unsigned short)((v.u + 0x7FFF + ((v.u >> 16) & 1)) >> 16);  // RNE
}
static __device__ __forceinline__ float bflo(unsigned int u) {
    union { unsigned int u; float f; } v; v.u = u << 16; return v.f;
}
static __device__ __forceinline__ float bfhi(unsigned int u) {
    union { unsigned int u; float f; } v; v.u = u & 0xFFFF0000u; return v.f;
}

// ---------------- feat_s -> pixel-major bf16 fsT[(b*1024+px)*128 + c]
__global__ __launch_bounds__(256) void k_prepfs(const float* __restrict__ fs,
        uint4* __restrict__ fsT4) {
    __shared__ unsigned short st[64 * 136];
    unsigned int* st32 = (unsigned int*)st;
    const int t = threadIdx.x;
    const int b = blockIdx.x >> 4;
    const int p0 = (blockIdx.x & 15) << 6;
    for (int i = t; i < 64 * 64; i += 256) {
        int c2 = i >> 6, px = i & 63;
        float v0 = fs[(((b << 7) + 2 * c2) << 10) + p0 + px];
        float v1 = fs[(((b << 7) + 2 * c2 + 1) << 10) + p0 + px];
        st32[px * 68 + c2] = (unsigned int)f2bf(v0) | ((unsigned int)f2bf(v1) << 16);
    }
    __syncthreads();
    for (int i = t; i < 64 * 16; i += 256) {
        int px = i >> 4, q = i & 15;
        fsT4[(((b << 10) + p0 + px) << 4) + q] = ((const uint4*)(st + px * 136))[q];
    }
}

// ---------------- generic B-frag pack: dst[(kk*NT+nt)*64+lane] (uint4 units)
__global__ __launch_bounds__(256) void k_pack(const float* __restrict__ W,
        unsigned short* __restrict__ dst, int K, int NT, int scaleFrom, int total) {
    int idx = blockIdx.x * 256 + threadIdx.x;
    if (idx >= total) return;
    int lane = idx & 63;
    int r = idx >> 6;
    int nt = r % NT;
    int kk = r / NT;
    int o = nt * 16 + (lane & 15);
    int k0 = kk * 32 + (lane >> 4) * 8;
    unsigned short tmp[8];
#pragma unroll
    for (int j = 0; j < 8; j++) {
        int k = k0 + j;
        float f = W[o * K + k];
        if (k >= scaleFrom) f *= 2.0f;
        tmp[j] = f2bf(f);
    }
    ((uint4*)dst)[idx] = *(const uint4*)tmp;
}

// ---------------- W_dcn pack: K ordering k = (g*9+tap)*16 + c, N=64 (NT=4)
__global__ __launch_bounds__(256) void k_packdcn(const float* __restrict__ Wd,
        unsigned short* __restrict__ dst) {
    int idx = blockIdx.x * 256 + threadIdx.x;
    if (idx >= 36 * 4 * 64) return;
    int lane = idx & 63;
    int r = idx >> 6;
    int nt = r & 3;
    int kk = r >> 2;
    int o = nt * 16 + (lane & 15);
    int k0 = kk * 32 + (lane >> 4) * 8;
    unsigned short tmp[8];
#pragma unroll
    for (int j = 0; j < 8; j++) {
        int k = k0 + j;
        int g = k / 144;
        int rem = k - g * 144;
        int tap = rem >> 4;
        int c = rem & 15;
        tmp[j] = f2bf(Wd[(o * 128 + g * 16 + c) * 9 + tap]);
    }
    ((uint4*)dst)[idx] = *(const uint4*)tmp;
}

// ---------------- W_om pack: K = tap*128 + c, N=224
__global__ __launch_bounds__(256) void k_prepw(const float* __restrict__ Wom,
        unsigned short* __restrict__ Wb2) {
    int idx = blockIdx.x * 256 + threadIdx.x;
    if (idx >= 9 * 4 * 14 * 64) return;
    int lane = idx & 63;
    int t2 = idx >> 6;
    int nt = t2 % 14;
    int cc = (t2 / 14) % 4;
    int tap = t2 / 56;
    int o = nt * 16 + (lane & 15);
    int c0 = cc * 32 + (lane >> 4) * 8;
    unsigned short tmp[8];
#pragma unroll
    for (int j = 0; j < 8; j++) {
        float v = (o < 216) ? Wom[(o * 128 + (c0 + j)) * 9 + tap] : 0.0f;
        tmp[j] = f2bf(v);
    }
    ((uint4*)Wb2)[idx] = *(const uint4*)tmp;
}

// ---------------- k12: fused fsm GEMM (K=128) + off GEMM (K=256)  (round-3, verified)
__global__ __launch_bounds__(256) void k12(const float* __restrict__ feat_l,
        const uint4* __restrict__ fsT4,
        const unsigned short* __restrict__ wbf, const unsigned short* __restrict__ wbo,
        const float* __restrict__ s_fsm, const float* __restrict__ b_fsm,
        const float* __restrict__ s_off, const float* __restrict__ b_off,
        float* __restrict__ feat_arm, unsigned short* __restrict__ offT) {
    __shared__ unsigned short A1[64 * 136];
    __shared__ unsigned short A2[64 * 264];
    float* E32 = (float*)A1;
    const int t = threadIdx.x;
    const int b = blockIdx.x >> 6;
    const int h = blockIdx.x & 63;
    const int hw0 = h << 6;
    unsigned int* A1w = (unsigned int*)A1;
    for (int i = t; i < 64 * 64; i += 256) {
        int c2 = i >> 6, px = i & 63;
        float v0 = feat_l[(((b << 7) + 2 * c2) << 12) + hw0 + px];
        float v1 = feat_l[(((b << 7) + 2 * c2 + 1) << 12) + hw0 + px];
        A1w[px * 68 + c2] = (unsigned int)f2bf(v0) | ((unsigned int)f2bf(v1) << 16);
    }
    {
        const int h2 = h >> 1;
        for (int i = t; i < 32 * 16; i += 256) {
            int px2 = i >> 4, q = i & 15;
            uint4 v = fsT4[(((b << 10) + (h2 << 5) + px2) << 4) + q];
            ((uint4*)(A2 + (2 * px2) * 264 + 128))[q] = v;
            ((uint4*)(A2 + (2 * px2 + 1) * 264 + 128))[q] = v;
        }
    }
    __syncthreads();
    const int lane = t & 63;
    const int wid = __builtin_amdgcn_readfirstlane(t >> 6);
    const int m = lane & 15, ko = lane >> 4;
    f32x4 acc[8];
#pragma unroll
    for (int nt = 0; nt < 8; nt++) acc[nt] = (f32x4){0.f, 0.f, 0.f, 0.f};
#pragma unroll
    for (int kk = 0; kk < 4; kk++) {
        short8 av = *(const short8*)(A1 + (wid * 16 + m) * 136 + kk * 32 + ko * 8);
        const uint4* wb = (const uint4*)wbf + (kk * 8) * 64 + lane;
#pragma unroll
        for (int nt = 0; nt < 8; nt++) {
            uint4 bu = wb[nt * 64];
            acc[nt] = __builtin_amdgcn_mfma_f32_16x16x32_bf16(av, *(short8*)&bu, acc[nt], 0, 0, 0);
        }
    }
#pragma unroll
    for (int nt = 0; nt < 8; nt++) {
        int o = nt * 16 + m;
        float sc = s_fsm[o], bi = b_fsm[o];
#pragma unroll
        for (int r = 0; r < 4; r++) {
            float v = fmaf(acc[nt][r], sc, bi);
            v = v > 0.f ? v : 0.f;
            acc[nt][r] = v;
            A2[(wid * 16 + ko * 4 + r) * 264 + o] = f2bf(v);
        }
    }
#pragma unroll 1
    for (int half = 0; half < 2; half++) {
        __syncthreads();
#pragma unroll
        for (int nt2 = 0; nt2 < 4; nt2++) {
            int nt = half * 4 + nt2;
#pragma unroll
            for (int r = 0; r < 4; r++)
                E32[(wid * 16 + ko * 4 + r) * 67 + nt2 * 16 + m] = acc[nt][r];
        }
        __syncthreads();
        for (int i = t; i < 4096; i += 256) {
            int ol = i >> 6, pp = i & 63;
            feat_arm[(((b << 7) + half * 64 + ol) << 12) + hw0 + pp] = E32[pp * 67 + ol];
        }
    }
    __syncthreads();
    f32x4 acc2[8];
#pragma unroll
    for (int nt = 0; nt < 8; nt++) acc2[nt] = (f32x4){0.f, 0.f, 0.f, 0.f};
#pragma unroll
    for (int kk = 0; kk < 8; kk++) {
        short8 av = *(const short8*)(A2 + (wid * 16 + m) * 264 + kk * 32 + ko * 8);
        const uint4* wb = (const uint4*)wbo + (kk * 8) * 64 + lane;
#pragma unroll
        for (int nt = 0; nt < 8; nt++) {
            uint4 bu = wb[nt * 64];
            acc2[nt] = __builtin_amdgcn_mfma_f32_16x16x32_bf16(av, *(short8*)&bu, acc2[nt], 0, 0, 0);
        }
    }
    __syncthreads();
#pragma unroll
    for (int nt = 0; nt < 8; nt++) {
        int o = nt * 16 + m;
        float sc = s_off[o], bi = b_off[o];
#pragma unroll
        for (int r = 0; r < 4; r++) {
            float v = fmaf(acc2[nt][r], sc, bi);
            v = v > 0.f ? v : 0.f;
            A2[(wid * 16 + ko * 4 + r) * 264 + o] = f2bf(v);
        }
    }
    __syncthreads();
    for (int i = t; i < 64 * 16; i += 256) {
        int px = i >> 4, q = i & 15;
        ((uint4*)offT)[(((b << 12) + hw0 + px) << 4) + q] = ((const uint4*)(A2 + px * 264))[q];
    }
}

// ---------------- k_om v3: LDS-staged double-buffered implicit-GEMM conv3x3
// Grid 256 blocks (1/CU): block = 2 image rows (128 px). 4 waves = 2 mg x 2 nh.
// Per wave: mt=4 M-tiles x nt=7 N-tiles (112 acc VGPRs). 18 phases of (tap, cc-pair);
// B-fragments (28.7KB/phase) double-buffered in LDS via register prefetch.
// A-fragments read directly from pixel-major offT (one predicated uint4 each).
__global__ __launch_bounds__(256, 1) void k_om(const unsigned short* __restrict__ offT,
        const unsigned short* __restrict__ Wb2, const float* __restrict__ bom,
        float* __restrict__ om) {
    __shared__ uint4 Wlds[2][1792];        // 2 x 28672 B
    const uint4* W4 = (const uint4*)Wb2;
    const uint4* offT4 = (const uint4*)offT;
    const int t = threadIdx.x;
    const int lane = t & 63;
    const int wid = __builtin_amdgcn_readfirstlane(t >> 6);
    const int mg = wid & 1, nh = wid >> 1;
    const int b = blockIdx.x >> 5;
    const int h0 = (blockIdx.x & 31) << 1;
    const int m = lane & 15, ko = lane >> 4;
    const int hrow = h0 + mg;               // wave-uniform output row
    const int pixbase = (b << 12) + (hrow << 6);

    f32x4 acc[28];
#pragma unroll
    for (int i = 0; i < 28; i++) acc[i] = (f32x4){0.f, 0.f, 0.f, 0.f};

    // prologue: prefetch phase 0 (tap0, cc{0,1}) and commit to buffer 0
    uint4 pre[7];
#pragma unroll
    for (int j = 0; j < 7; j++) pre[j] = W4[j * 256 + t];
#pragma unroll
    for (int j = 0; j < 7; j++) Wlds[0][j * 256 + t] = pre[j];
    __syncthreads();

    int cur = 0;
#pragma unroll 1
    for (int p = 0; p < 18; p++) {
        const int tap = p >> 1;
        const int ch = p & 1;
        const int dy = tap / 3, dx = tap - dy * 3;
        // prefetch next phase's B chunk
        if (p < 17) {
            const int np = p + 1;
            const int nb = (((np >> 1) << 2) + ((np & 1) << 1)) * 896;
#pragma unroll
            for (int j = 0; j < 7; j++) pre[j] = W4[nb + j * 256 + t];
        }
        const int ys = hrow + dy - 1;
        const bool yok = (ys >= 0) && (ys < 64);
        const int abase = ((b << 12) + (ys << 6)) << 4;
#pragma unroll
        for (int ccl = 0; ccl < 2; ccl++) {
            const int cc = (ch << 1) + ccl;
            uint4 a4[4];
#pragma unroll
            for (int mt = 0; mt < 4; mt++) {
                int xs = mt * 16 + m + dx - 1;
                bool ok = yok && (xs >= 0) && (xs < 64);
                a4[mt] = make_uint4(0, 0, 0, 0);
                if (ok) a4[mt] = offT4[abase + (xs << 4) + (cc << 2) + ko];
            }
            const uint4* bb = &Wlds[cur][((ccl * 14 + nh * 7) << 6) + lane];
#pragma unroll
            for (int nt2 = 0; nt2 < 7; nt2++) {
                uint4 bu = bb[nt2 << 6];
                short8 bv = *(short8*)&bu;
#pragma unroll
                for (int mt = 0; mt < 4; mt++) {
                    acc[mt * 7 + nt2] = __builtin_amdgcn_mfma_f32_16x16x32_bf16(
                        *(short8*)&a4[mt], bv, acc[mt * 7 + nt2], 0, 0, 0);
                }
            }
        }
        if (p < 17) {
#pragma unroll
            for (int j = 0; j < 7; j++) Wlds[cur ^ 1][j * 256 + t] = pre[j];
        }
        __syncthreads();
        cur ^= 1;
    }

    // epilogue: direct float4 stores; rows r=0..3 are consecutive pixels
#pragma unroll
    for (int nt2 = 0; nt2 < 7; nt2++) {
        int o = ((nh * 7 + nt2) << 4) + m;
        if (o < 216) {
            float bv = bom[o];
#pragma unroll
            for (int mt = 0; mt < 4; mt++) {
                f32x4 v = acc[mt * 7 + nt2];
                float4 s = make_float4(v[0] + bv, v[1] + bv, v[2] + bv, v[3] + bv);
                *(float4*)(om + (b * 216 + o) * 4096 + (hrow << 6) + mt * 16 + (ko << 2)) = s;
            }
        }
    }
}

// ---------------- k45: fused DCNv2 + cat GEMM  (round-3, verified)
__global__ __launch_bounds__(512) void k45(const uint4* __restrict__ fsT4,
        const float* __restrict__ om, const unsigned short* __restrict__ wbd,
        const float* __restrict__ bd, const unsigned short* __restrict__ wbc,
        const float* __restrict__ s_cat, const float* __restrict__ b_cat,
        const float* __restrict__ feat_arm, float* __restrict__ feat) {
    __shared__ float R1[64 * 67];
    __shared__ unsigned short A3[64 * 72];
    const int t = threadIdx.x;
    const int lane = t & 63;
    const int wid = __builtin_amdgcn_readfirstlane(t >> 6);
    const int mt = wid & 3, kh = wid >> 2;
    const int b = blockIdx.x >> 6;
    const int h = blockIdx.x & 63;
    const int hw0 = h << 6;
    const int m = lane & 15, ko = lane >> 4;
    const int px = mt * 16 + m;
    const int hw = hw0 + px;
    const float fh = (float)h, fw = (float)px;
    const int ombase = (b * 216) * 4096 + hw;
    const int pb_ = b << 10;
    f32x4 acc[4];
#pragma unroll
    for (int nt = 0; nt < 4; nt++) acc[nt] = (f32x4){0.f, 0.f, 0.f, 0.f};
#pragma unroll 1
    for (int kk = 0; kk < 18; kk++) {
        int k0 = kh * 576 + kk * 32 + ko * 8;
        int g = k0 / 144;
        int rem = k0 - g * 144;
        int tap = rem >> 4;
        int c0 = rem & 15;
        int ch = g * 9 + tap;
        float oy = om[ombase + ch * 4096];
        float ox = om[ombase + (72 + ch) * 4096];
        float mmv = om[ombase + (144 + ch) * 4096];
        mmv = 1.0f / (1.0f + __expf(-mmv));
        float py = fh + (float)(tap / 3 - 1) + oy;
        float pxx = fw + (float)(tap % 3 - 1) + ox;
        float y0f = floorf(py), x0f = floorf(pxx);
        float tyf = py - y0f, txf = pxx - x0f;
        int y0i = (int)y0f, x0i = (int)x0f;
        int y1i = y0i + 1, x1i = x0i + 1;
        bool vy0 = (y0i >= 0) && (y0i < 64);
        bool vy1 = (y1i >= 0) && (y1i < 64);
        bool vx0 = (x0i >= 0) && (x0i < 64);
        bool vx1 = (x1i >= 0) && (x1i < 64);
        float w00 = (vy0 && vx0) ? (1.0f - tyf) * (1.0f - txf) * mmv : 0.0f;
        float w01 = (vy0 && vx1) ? (1.0f - tyf) * txf * mmv : 0.0f;
        float w10 = (vy1 && vx0) ? tyf * (1.0f - txf) * mmv : 0.0f;
        float w11 = (vy1 && vx1) ? tyf * txf * mmv : 0.0f;
        int yc0 = y0i < 0 ? 0 : (y0i > 63 ? 63 : y0i);
        int yc1 = y1i < 0 ? 0 : (y1i > 63 ? 63 : y1i);
        int xc0 = x0i < 0 ? 0 : (x0i > 63 ? 63 : x0i);
        int xc1 = x1i < 0 ? 0 : (x1i > 63 ? 63 : x1i);
        int row0 = (yc0 >> 1) << 5, row1 = (yc1 >> 1) << 5;
        int ci = g * 2 + (c0 >> 3);
        uint4 A00 = fsT4[((pb_ + row0 + (xc0 >> 1)) << 4) + ci];
        uint4 A01 = fsT4[((pb_ + row0 + (xc1 >> 1)) << 4) + ci];
        uint4 A10 = fsT4[((pb_ + row1 + (xc0 >> 1)) << 4) + ci];
        uint4 A11 = fsT4[((pb_ + row1 + (xc1 >> 1)) << 4) + ci];
        union { short8 s; unsigned short u[8]; } av;
#define DOU(idx, comp) { \
        unsigned int q00 = A00.comp, q01 = A01.comp, q10 = A10.comp, q11 = A11.comp; \
        float vl = w00 * bflo(q00) + w01 * bflo(q01) + w10 * bflo(q10) + w11 * bflo(q11); \
        float vh = w00 * bfhi(q00) + w01 * bfhi(q01) + w10 * bfhi(q10) + w11 * bfhi(q11); \
        av.u[2 * idx] = f2bf(vl); av.u[2 * idx + 1] = f2bf(vh); }
        DOU(0, x) DOU(1, y) DOU(2, z) DOU(3, w)
#undef DOU
        const uint4* wb = (const uint4*)wbd + ((kh * 18 + kk) * 4) * 64 + lane;
#pragma unroll
        for (int nt = 0; nt < 4; nt++) {
            uint4 bu = wb[nt * 64];
            acc[nt] = __builtin_amdgcn_mfma_f32_16x16x32_bf16(av.s, *(short8*)&bu, acc[nt], 0, 0, 0);
        }
    }
    if (kh == 1) {
#pragma unroll
        for (int nt = 0; nt < 4; nt++)
#pragma unroll
            for (int r = 0; r < 4; r++)
                R1[(mt * 16 + ko * 4 + r) * 67 + nt * 16 + m] = acc[nt][r];
    }
    __syncthreads();
    if (kh == 0) {
#pragma unroll
        for (int nt = 0; nt < 4; nt++) {
            int o = nt * 16 + m;
            float bv = bd[o];
#pragma unroll
            for (int r = 0; r < 4; r++) {
                int prow = mt * 16 + ko * 4 + r;
                float v = acc[nt][r] + R1[prow * 67 + o] + bv;
                v = v > 0.f ? v : 0.f;
                A3[prow * 72 + o] = f2bf(v);
            }
        }
    }
    __syncthreads();
    f32x4 accc[4];
#pragma unroll
    for (int nt = 0; nt < 4; nt++) accc[nt] = (f32x4){0.f, 0.f, 0.f, 0.f};
#pragma unroll
    for (int kk2 = 0; kk2 < 2; kk2++) {
        short8 av = *(const short8*)(A3 + (mt * 16 + m) * 72 + kk2 * 32 + ko * 8);
        const uint4* wb = (const uint4*)wbc + (kk2 * 8 + kh * 4) * 64 + lane;
#pragma unroll
        for (int nt = 0; nt < 4; nt++) {
            uint4 bu = wb[nt * 64];
            accc[nt] = __builtin_amdgcn_mfma_f32_16x16x32_bf16(av, *(short8*)&bu, accc[nt], 0, 0, 0);
        }
    }
#pragma unroll 1
    for (int half = 0; half < 2; half++) {
        __syncthreads();
        if (kh == half) {
#pragma unroll
            for (int nt = 0; nt < 4; nt++) {
                int ol = nt * 16 + m;
                int o = half * 64 + ol;
                float sc = s_cat[o], bi = b_cat[o];
#pragma unroll
                for (int r = 0; r < 4; r++) {
                    float v = fmaf(accc[nt][r], sc, bi);
                    v = v > 0.f ? v : 0.f;
                    R1[(mt * 16 + ko * 4 + r) * 67 + ol] = v;
                }
            }
        }
        __syncthreads();
        for (int i = t; i < 4096; i += 512) {
            int ol = i >> 6, pp = i & 63;
            int gidx = (((b << 7) + half * 64 + ol) << 12) + hw0 + pp;
            feat[gidx] = R1[pp * 67 + ol] + feat_arm[gidx];
        }
    }
}

extern "C" void kernel_launch(void* const* d_in, const int* in_sizes, int n_in,
                              void* d_out, int out_size, void* d_ws, size_t ws_size,
                              hipStream_t stream) {
    const float* feat_l = (const float*)d_in[0];
    const float* feat_s = (const float*)d_in[1];
    const float* W_fsm  = (const float*)d_in[2];
    const float* s_fsm  = (const float*)d_in[3];
    const float* b_fsm  = (const float*)d_in[4];
    const float* W_off  = (const float*)d_in[5];
    const float* s_off  = (const float*)d_in[6];
    const float* b_off  = (const float*)d_in[7];
    const float* W_om   = (const float*)d_in[8];
    const float* b_om   = (const float*)d_in[9];
    const float* W_dcn  = (const float*)d_in[10];
    const float* b_dcn  = (const float*)d_in[11];
    const float* W_cat  = (const float*)d_in[12];
    const float* s_cat  = (const float*)d_in[13];
    const float* b_cat  = (const float*)d_in[14];

    float* feat     = (float*)d_out;
    float* feat_arm = feat + 4194304;

    float* ws = (float*)d_ws;
    unsigned short* offT = (unsigned short*)ws;            // 2,097,152 f
    float* om_ws = ws + 2097152;                           // 7,077,888 f
    uint4* fsT4  = (uint4*)(ws + 9175040);                 //   524,288 f
    unsigned short* wb2   = (unsigned short*)(ws + 9699328);   // 129,024 f
    unsigned short* wbfsm = (unsigned short*)(ws + 9828352);   //   8,192 f
    unsigned short* wboff = (unsigned short*)(ws + 9836544);   //  16,384 f
    unsigned short* wbcat = (unsigned short*)(ws + 9852928);   //   4,096 f
    unsigned short* wbdcn = (unsigned short*)(ws + 9857024);   //  36,864 f

    k_prepfs<<<128, 256, 0, stream>>>(feat_s, fsT4);
    k_pack<<<8, 256, 0, stream>>>(W_fsm, wbfsm, 128, 8, 1 << 30, 2048);
    k_pack<<<16, 256, 0, stream>>>(W_off, wboff, 256, 8, 128, 4096);
    k_pack<<<4, 256, 0, stream>>>(W_cat, wbcat, 64, 8, 1 << 30, 1024);
    k_packdcn<<<36, 256, 0, stream>>>(W_dcn, wbdcn);
    k_prepw<<<126, 256, 0, stream>>>(W_om, wb2);

    k12<<<512, 256, 0, stream>>>(feat_l, fsT4, wbfsm, wboff,
                                 s_fsm, b_fsm, s_off, b_off, feat_arm, offT);
    k_om<<<256, 256, 0, stream>>>(offT, wb2, b_om, om_ws);
    k45<<<512, 512, 0, stream>>>(fsT4, om_ws, wbdcn, b_dcn, wbcat,
                                 s_cat, b_cat, feat_arm, feat);
}

// Round 5
// 201.263 us; speedup vs baseline: 3.4746x; 1.2130x over previous
//
#include <hip/hip_runtime.h>

// B=8, C=128, H=W=64, G=8, K=9, Cg=16, Cd=64. NCHW, HW=4096.
// MFMA conventions (verified in-problem, round 2):
//   A-frag: lane&15 = m, k-octet = (lane>>4)*8 + j
//   B-frag: lane&15 = n, k-octet = (lane>>4)*8 + j
//   C/D:    col = lane&15 (n), row = (lane>>4)*4 + r (m)

typedef __attribute__((ext_vector_type(8))) short short8;
typedef __attribute__((ext_vector_type(4))) float f32x4;

static __device__ __forceinline__ unsigned short f2bf(float x) {
    union { float f; unsigned int u; } v; v.f = x;
    return (unsigned short)((v.u + 0x7FFF + ((v.u >> 16) & 1)) >> 16);  // RNE
}
static __device__ __forceinline__ float bflo(unsigned int u) {
    union { unsigned int u; float f; } v; v.u = u << 16; return v.f;
}
static __device__ __forceinline__ float bfhi(unsigned int u) {
    union { unsigned int u; float f; } v; v.u = u & 0xFFFF0000u; return v.f;
}

// ---------------- feat_s -> pixel-major bf16 fsT[(b*1024+px)*128 + c]
__global__ __launch_bounds__(256) void k_prepfs(const float* __restrict__ fs,
        uint4* __restrict__ fsT4) {
    __shared__ unsigned short st[64 * 136];
    unsigned int* st32 = (unsigned int*)st;
    const int t = threadIdx.x;
    const int b = blockIdx.x >> 4;
    const int p0 = (blockIdx.x & 15) << 6;
    for (int i = t; i < 64 * 64; i += 256) {
        int c2 = i >> 6, px = i & 63;
        float v0 = fs[(((b << 7) + 2 * c2) << 10) + p0 + px];
        float v1 = fs[(((b << 7) + 2 * c2 + 1) << 10) + p0 + px];
        st32[px * 68 + c2] = (unsigned int)f2bf(v0) | ((unsigned int)f2bf(v1) << 16);
    }
    __syncthreads();
    for (int i = t; i < 64 * 16; i += 256) {
        int px = i >> 4, q = i & 15;
        fsT4[(((b << 10) + p0 + px) << 4) + q] = ((const uint4*)(st + px * 136))[q];
    }
}

// ---------------- all weight packs in ONE kernel (saves 4 launches)
// segments (uint4 units): wbfsm 2048 | wboff 4096 | wbcat 1024 | wbdcn 9216 | wb2 36864
__global__ __launch_bounds__(256) void k_packall(
        const float* __restrict__ W_fsm, const float* __restrict__ W_off,
        const float* __restrict__ W_cat, const float* __restrict__ W_dcn,
        const float* __restrict__ W_om,
        unsigned short* __restrict__ wbfsm, unsigned short* __restrict__ wboff,
        unsigned short* __restrict__ wbcat, unsigned short* __restrict__ wbdcn,
        unsigned short* __restrict__ wb2) {
    int idx = blockIdx.x * 256 + threadIdx.x;
    int lane = idx & 63;
    int ml = lane & 15, kl = (lane >> 4) * 8;
    unsigned short tmp[8];
    if (idx < 2048) {                       // wbfsm: K=128, NT=8
        int r = idx >> 6;
        int o = (r % 8) * 16 + ml, k0 = (r / 8) * 32 + kl;
#pragma unroll
        for (int j = 0; j < 8; j++) tmp[j] = f2bf(W_fsm[o * 128 + k0 + j]);
        ((uint4*)wbfsm)[idx] = *(const uint4*)tmp;
    } else if (idx < 6144) {                // wboff: K=256, NT=8, x2 for k>=128
        int i2 = idx - 2048;
        int r = i2 >> 6;
        int o = (r % 8) * 16 + ml, k0 = (r / 8) * 32 + kl;
#pragma unroll
        for (int j = 0; j < 8; j++) {
            int k = k0 + j;
            float f = W_off[o * 256 + k];
            if (k >= 128) f *= 2.0f;
            tmp[j] = f2bf(f);
        }
        ((uint4*)wboff)[i2] = *(const uint4*)tmp;
    } else if (idx < 7168) {                // wbcat: K=64, NT=8
        int i2 = idx - 6144;
        int r = i2 >> 6;
        int o = (r % 8) * 16 + ml, k0 = (r / 8) * 32 + kl;
#pragma unroll
        for (int j = 0; j < 8; j++) tmp[j] = f2bf(W_cat[o * 64 + k0 + j]);
        ((uint4*)wbcat)[i2] = *(const uint4*)tmp;
    } else if (idx < 16384) {               // wbdcn: K=1152 (g,tap,c), NT=4
        int i2 = idx - 7168;
        int r = i2 >> 6;
        int o = (r & 3) * 16 + ml, k0 = (r >> 2) * 32 + kl;
#pragma unroll
        for (int j = 0; j < 8; j++) {
            int k = k0 + j;
            int g = k / 144;
            int rem = k - g * 144;
            tmp[j] = f2bf(W_dcn[(o * 128 + g * 16 + (rem & 15)) * 9 + (rem >> 4)]);
        }
        ((uint4*)wbdcn)[i2] = *(const uint4*)tmp;
    } else if (idx < 53248) {               // wb2: K=(tap,c), NT=16 (N=256, pad o>=216)
        int i2 = idx - 16384;
        int r = i2 >> 6;
        int nt = r & 15, kk = r >> 4;
        int tap = kk >> 2, cc = kk & 3;
        int o = nt * 16 + ml;
        int c0 = cc * 32 + kl;
#pragma unroll
        for (int j = 0; j < 8; j++) {
            float v = (o < 216) ? W_om[(o * 128 + (c0 + j)) * 9 + tap] : 0.0f;
            tmp[j] = f2bf(v);
        }
        ((uint4*)wb2)[i2] = *(const uint4*)tmp;
    }
}

// ---------------- k12: fused fsm GEMM (K=128) + off GEMM (K=256)  (round-3, verified)
__global__ __launch_bounds__(256) void k12(const float* __restrict__ feat_l,
        const uint4* __restrict__ fsT4,
        const unsigned short* __restrict__ wbf, const unsigned short* __restrict__ wbo,
        const float* __restrict__ s_fsm, const float* __restrict__ b_fsm,
        const float* __restrict__ s_off, const float* __restrict__ b_off,
        float* __restrict__ feat_arm, unsigned short* __restrict__ offT) {
    __shared__ unsigned short A1[64 * 136];
    __shared__ unsigned short A2[64 * 264];
    float* E32 = (float*)A1;
    const int t = threadIdx.x;
    const int b = blockIdx.x >> 6;
    const int h = blockIdx.x & 63;
    const int hw0 = h << 6;
    unsigned int* A1w = (unsigned int*)A1;
    for (int i = t; i < 64 * 64; i += 256) {
        int c2 = i >> 6, px = i & 63;
        float v0 = feat_l[(((b << 7) + 2 * c2) << 12) + hw0 + px];
        float v1 = feat_l[(((b << 7) + 2 * c2 + 1) << 12) + hw0 + px];
        A1w[px * 68 + c2] = (unsigned int)f2bf(v0) | ((unsigned int)f2bf(v1) << 16);
    }
    {
        const int h2 = h >> 1;
        for (int i = t; i < 32 * 16; i += 256) {
            int px2 = i >> 4, q = i & 15;
            uint4 v = fsT4[(((b << 10) + (h2 << 5) + px2) << 4) + q];
            ((uint4*)(A2 + (2 * px2) * 264 + 128))[q] = v;
            ((uint4*)(A2 + (2 * px2 + 1) * 264 + 128))[q] = v;
        }
    }
    __syncthreads();
    const int lane = t & 63;
    const int wid = __builtin_amdgcn_readfirstlane(t >> 6);
    const int m = lane & 15, ko = lane >> 4;
    f32x4 acc[8];
#pragma unroll
    for (int nt = 0; nt < 8; nt++) acc[nt] = (f32x4){0.f, 0.f, 0.f, 0.f};
#pragma unroll
    for (int kk = 0; kk < 4; kk++) {
        short8 av = *(const short8*)(A1 + (wid * 16 + m) * 136 + kk * 32 + ko * 8);
        const uint4* wb = (const uint4*)wbf + (kk * 8) * 64 + lane;
#pragma unroll
        for (int nt = 0; nt < 8; nt++) {
            uint4 bu = wb[nt * 64];
            acc[nt] = __builtin_amdgcn_mfma_f32_16x16x32_bf16(av, *(short8*)&bu, acc[nt], 0, 0, 0);
        }
    }
#pragma unroll
    for (int nt = 0; nt < 8; nt++) {
        int o = nt * 16 + m;
        float sc = s_fsm[o], bi = b_fsm[o];
#pragma unroll
        for (int r = 0; r < 4; r++) {
            float v = fmaf(acc[nt][r], sc, bi);
            v = v > 0.f ? v : 0.f;
            acc[nt][r] = v;
            A2[(wid * 16 + ko * 4 + r) * 264 + o] = f2bf(v);
        }
    }
#pragma unroll 1
    for (int half = 0; half < 2; half++) {
        __syncthreads();
#pragma unroll
        for (int nt2 = 0; nt2 < 4; nt2++) {
            int nt = half * 4 + nt2;
#pragma unroll
            for (int r = 0; r < 4; r++)
                E32[(wid * 16 + ko * 4 + r) * 67 + nt2 * 16 + m] = acc[nt][r];
        }
        __syncthreads();
        for (int i = t; i < 4096; i += 256) {
            int ol = i >> 6, pp = i & 63;
            feat_arm[(((b << 7) + half * 64 + ol) << 12) + hw0 + pp] = E32[pp * 67 + ol];
        }
    }
    __syncthreads();
    f32x4 acc2[8];
#pragma unroll
    for (int nt = 0; nt < 8; nt++) acc2[nt] = (f32x4){0.f, 0.f, 0.f, 0.f};
#pragma unroll
    for (int kk = 0; kk < 8; kk++) {
        short8 av = *(const short8*)(A2 + (wid * 16 + m) * 264 + kk * 32 + ko * 8);
        const uint4* wb = (const uint4*)wbo + (kk * 8) * 64 + lane;
#pragma unroll
        for (int nt = 0; nt < 8; nt++) {
            uint4 bu = wb[nt * 64];
            acc2[nt] = __builtin_amdgcn_mfma_f32_16x16x32_bf16(av, *(short8*)&bu, acc2[nt], 0, 0, 0);
        }
    }
    __syncthreads();
#pragma unroll
    for (int nt = 0; nt < 8; nt++) {
        int o = nt * 16 + m;
        float sc = s_off[o], bi = b_off[o];
#pragma unroll
        for (int r = 0; r < 4; r++) {
            float v = fmaf(acc2[nt][r], sc, bi);
            v = v > 0.f ? v : 0.f;
            A2[(wid * 16 + ko * 4 + r) * 264 + o] = f2bf(v);
        }
    }
    __syncthreads();
    for (int i = t; i < 64 * 16; i += 256) {
        int px = i >> 4, q = i & 15;
        ((uint4*)offT)[(((b << 12) + hw0 + px) << 4) + q] = ((const uint4*)(A2 + px * 264))[q];
    }
}

// ---------------- k_om v5: barrier-free K-loop implicit-GEMM conv3x3
// 512 blocks x 4 waves; block = 1 row (64 px) x N=256 (padded). Wave owns N-quarter
// (4 N-tiles) -> zero cross-wave B redundancy. A staged ONCE in LDS (3 rows, 1-px
// x-pad, stride 136 vs banks). 36 k-steps, no barriers -> deep vmcnt pipelining.
__global__ __launch_bounds__(256, 3) void k_om(const unsigned short* __restrict__ offT,
        const unsigned short* __restrict__ Wb2, const float* __restrict__ bom,
        float* __restrict__ om) {
    __shared__ unsigned short st[3 * 66 * 136];   // 53856 B
    const uint4* offT4 = (const uint4*)offT;
    const uint4* W4 = (const uint4*)Wb2;
    const int t = threadIdx.x;
    const int b = blockIdx.x >> 6;
    const int h = blockIdx.x & 63;
    // stage 3 input rows (h-1,h,h+1) x 66 px (1-px pad each side), zero-filled OOB
    for (int i = t; i < 3 * 66 * 16; i += 256) {
        int q = i & 15;
        int rp = i >> 4;                    // r*66 + p
        int r = rp / 66, p = rp - r * 66;
        int gy = h + r - 1, gx = p - 1;
        uint4 v = make_uint4(0, 0, 0, 0);
        if (gy >= 0 && gy < 64 && gx >= 0 && gx < 64)
            v = offT4[((((b << 6) + gy) << 6) + gx) * 16 + q];
        ((uint4*)(st + rp * 136))[q] = v;
    }
    __syncthreads();
    const int lane = t & 63;
    const int nh = __builtin_amdgcn_readfirstlane(t >> 6);   // N-quarter 0..3
    const int m = lane & 15, ko = lane >> 4;
    f32x4 acc[16];
#pragma unroll
    for (int i = 0; i < 16; i++) acc[i] = (f32x4){0.f, 0.f, 0.f, 0.f};
#pragma unroll 4
    for (int kk = 0; kk < 36; kk++) {
        const int tap = kk >> 2, cc = kk & 3;
        const int dy = tap / 3, dx = tap - dy * 3;
        uint4 b4[4];
#pragma unroll
        for (int nt2 = 0; nt2 < 4; nt2++)
            b4[nt2] = W4[(((kk << 4) + (nh << 2) + nt2) << 6) + lane];
        short8 a8[4];
#pragma unroll
        for (int mt = 0; mt < 4; mt++) {
            int p = mt * 16 + m + dx;       // 0..65 (p=0 <-> xs=-1 pad)
            a8[mt] = *(const short8*)(st + (dy * 66 + p) * 136 + (cc << 5) + (ko << 3));
        }
#pragma unroll
        for (int nt2 = 0; nt2 < 4; nt2++)
#pragma unroll
            for (int mt = 0; mt < 4; mt++)
                acc[nt2 * 4 + mt] = __builtin_amdgcn_mfma_f32_16x16x32_bf16(
                    a8[mt], *(short8*)&b4[nt2], acc[nt2 * 4 + mt], 0, 0, 0);
    }
    // epilogue: D rows r=0..3 are consecutive pixels -> direct float4 stores
#pragma unroll
    for (int nt2 = 0; nt2 < 4; nt2++) {
        int o = (((nh << 2) + nt2) << 4) + m;
        if (o < 216) {
            float bv = bom[o];
#pragma unroll
            for (int mt = 0; mt < 4; mt++) {
                f32x4 v = acc[nt2 * 4 + mt];
                float4 s = make_float4(v[0] + bv, v[1] + bv, v[2] + bv, v[3] + bv);
                *(float4*)(om + ((b * 216 + o) << 12) + (h << 6) + (mt << 4) + (ko << 2)) = s;
            }
        }
    }
}

// ---------------- k45: fused DCNv2 + cat GEMM  (round-3, verified)
__global__ __launch_bounds__(512) void k45(const uint4* __restrict__ fsT4,
        const float* __restrict__ om, const unsigned short* __restrict__ wbd,
        const float* __restrict__ bd, const unsigned short* __restrict__ wbc,
        const float* __restrict__ s_cat, const float* __restrict__ b_cat,
        const float* __restrict__ feat_arm, float* __restrict__ feat) {
    __shared__ float R1[64 * 67];
    __shared__ unsigned short A3[64 * 72];
    const int t = threadIdx.x;
    const int lane = t & 63;
    const int wid = __builtin_amdgcn_readfirstlane(t >> 6);
    const int mt = wid & 3, kh = wid >> 2;
    const int b = blockIdx.x >> 6;
    const int h = blockIdx.x & 63;
    const int hw0 = h << 6;
    const int m = lane & 15, ko = lane >> 4;
    const int px = mt * 16 + m;
    const int hw = hw0 + px;
    const float fh = (float)h, fw = (float)px;
    const int ombase = (b * 216) * 4096 + hw;
    const int pb_ = b << 10;
    f32x4 acc[4];
#pragma unroll
    for (int nt = 0; nt < 4; nt++) acc[nt] = (f32x4){0.f, 0.f, 0.f, 0.f};
#pragma unroll 1
    for (int kk = 0; kk < 18; kk++) {
        int k0 = kh * 576 + kk * 32 + ko * 8;
        int g = k0 / 144;
        int rem = k0 - g * 144;
        int tap = rem >> 4;
        int c0 = rem & 15;
        int ch = g * 9 + tap;
        float oy = om[ombase + ch * 4096];
        float ox = om[ombase + (72 + ch) * 4096];
        float mmv = om[ombase + (144 + ch) * 4096];
        mmv = 1.0f / (1.0f + __expf(-mmv));
        float py = fh + (float)(tap / 3 - 1) + oy;
        float pxx = fw + (float)(tap % 3 - 1) + ox;
        float y0f = floorf(py), x0f = floorf(pxx);
        float tyf = py - y0f, txf = pxx - x0f;
        int y0i = (int)y0f, x0i = (int)x0f;
        int y1i = y0i + 1, x1i = x0i + 1;
        bool vy0 = (y0i >= 0) && (y0i < 64);
        bool vy1 = (y1i >= 0) && (y1i < 64);
        bool vx0 = (x0i >= 0) && (x0i < 64);
        bool vx1 = (x1i >= 0) && (x1i < 64);
        float w00 = (vy0 && vx0) ? (1.0f - tyf) * (1.0f - txf) * mmv : 0.0f;
        float w01 = (vy0 && vx1) ? (1.0f - tyf) * txf * mmv : 0.0f;
        float w10 = (vy1 && vx0) ? tyf * (1.0f - txf) * mmv : 0.0f;
        float w11 = (vy1 && vx1) ? tyf * txf * mmv : 0.0f;
        int yc0 = y0i < 0 ? 0 : (y0i > 63 ? 63 : y0i);
        int yc1 = y1i < 0 ? 0 : (y1i > 63 ? 63 : y1i);
        int xc0 = x0i < 0 ? 0 : (x0i > 63 ? 63 : x0i);
        int xc1 = x1i < 0 ? 0 : (x1i > 63 ? 63 : x1i);
        int row0 = (yc0 >> 1) << 5, row1 = (yc1 >> 1) << 5;
        int ci = g * 2 + (c0 >> 3);
        uint4 A00 = fsT4[((pb_ + row0 + (xc0 >> 1)) << 4) + ci];
        uint4 A01 = fsT4[((pb_ + row0 + (xc1 >> 1)) << 4) + ci];
        uint4 A10 = fsT4[((pb_ + row1 + (xc0 >> 1)) << 4) + ci];
        uint4 A11 = fsT4[((pb_ + row1 + (xc1 >> 1)) << 4) + ci];
        union { short8 s; unsigned short u[8]; } av;
#define DOU(idx, comp) { \
        unsigned int q00 = A00.comp, q01 = A01.comp, q10 = A10.comp, q11 = A11.comp; \
        float vl = w00 * bflo(q00) + w01 * bflo(q01) + w10 * bflo(q10) + w11 * bflo(q11); \
        float vh = w00 * bfhi(q00) + w01 * bfhi(q01) + w10 * bfhi(q10) + w11 * bfhi(q11); \
        av.u[2 * idx] = f2bf(vl); av.u[2 * idx + 1] = f2bf(vh); }
        DOU(0, x) DOU(1, y) DOU(2, z) DOU(3, w)
#undef DOU
        const uint4* wb = (const uint4*)wbd + ((kh * 18 + kk) * 4) * 64 + lane;
#pragma unroll
        for (int nt = 0; nt < 4; nt++) {
            uint4 bu = wb[nt * 64];
            acc[nt] = __builtin_amdgcn_mfma_f32_16x16x32_bf16(av.s, *(short8*)&bu, acc[nt], 0, 0, 0);
        }
    }
    if (kh == 1) {
#pragma unroll
        for (int nt = 0; nt < 4; nt++)
#pragma unroll
            for (int r = 0; r < 4; r++)
                R1[(mt * 16 + ko * 4 + r) * 67 + nt * 16 + m] = acc[nt][r];
    }
    __syncthreads();
    if (kh == 0) {
#pragma unroll
        for (int nt = 0; nt < 4; nt++) {
            int o = nt * 16 + m;
            float bv = bd[o];
#pragma unroll
            for (int r = 0; r < 4; r++) {
                int prow = mt * 16 + ko * 4 + r;
                float v = acc[nt][r] + R1[prow * 67 + o] + bv;
                v = v > 0.f ? v : 0.f;
                A3[prow * 72 + o] = f2bf(v);
            }
        }
    }
    __syncthreads();
    f32x4 accc[4];
#pragma unroll
    for (int nt = 0; nt < 4; nt++) accc[nt] = (f32x4){0.f, 0.f, 0.f, 0.f};
#pragma unroll
    for (int kk2 = 0; kk2 < 2; kk2++) {
        short8 av = *(const short8*)(A3 + (mt * 16 + m) * 72 + kk2 * 32 + ko * 8);
        const uint4* wb = (const uint4*)wbc + (kk2 * 8 + kh * 4) * 64 + lane;
#pragma unroll
        for (int nt = 0; nt < 4; nt++) {
            uint4 bu = wb[nt * 64];
            accc[nt] = __builtin_amdgcn_mfma_f32_16x16x32_bf16(av, *(short8*)&bu, accc[nt], 0, 0, 0);
        }
    }
#pragma unroll 1
    for (int half = 0; half < 2; half++) {
        __syncthreads();
        if (kh == half) {
#pragma unroll
            for (int nt = 0; nt < 4; nt++) {
                int ol = nt * 16 + m;
                int o = half * 64 + ol;
                float sc = s_cat[o], bi = b_cat[o];
#pragma unroll
                for (int r = 0; r < 4; r++) {
                    float v = fmaf(accc[nt][r], sc, bi);
                    v = v > 0.f ? v : 0.f;
                    R1[(mt * 16 + ko * 4 + r) * 67 + ol] = v;
                }
            }
        }
        __syncthreads();
        for (int i = t; i < 4096; i += 512) {
            int ol = i >> 6, pp = i & 63;
            int gidx = (((b << 7) + half * 64 + ol) << 12) + hw0 + pp;
            feat[gidx] = R1[pp * 67 + ol] + feat_arm[gidx];
        }
    }
}

extern "C" void kernel_launch(void* const* d_in, const int* in_sizes, int n_in,
                              void* d_out, int out_size, void* d_ws, size_t ws_size,
                              hipStream_t stream) {
    const float* feat_l = (const float*)d_in[0];
    const float* feat_s = (const float*)d_in[1];
    const float* W_fsm  = (const float*)d_in[2];
    const float* s_fsm  = (const float*)d_in[3];
    const float* b_fsm  = (const float*)d_in[4];
    const float* W_off  = (const float*)d_in[5];
    const float* s_off  = (const float*)d_in[6];
    const float* b_off  = (const float*)d_in[7];
    const float* W_om   = (const float*)d_in[8];
    const float* b_om   = (const float*)d_in[9];
    const float* W_dcn  = (const float*)d_in[10];
    const float* b_dcn  = (const float*)d_in[11];
    const float* W_cat  = (const float*)d_in[12];
    const float* s_cat  = (const float*)d_in[13];
    const float* b_cat  = (const float*)d_in[14];

    float* feat     = (float*)d_out;
    float* feat_arm = feat + 4194304;

    float* ws = (float*)d_ws;
    unsigned short* offT = (unsigned short*)ws;                // 2,097,152 f
    float* om_ws = ws + 2097152;                               // 7,077,888 f
    uint4* fsT4  = (uint4*)(ws + 9175040);                     //   524,288 f
    unsigned short* wb2   = (unsigned short*)(ws + 9699328);   //  147,456 f (36864 uint4)
    unsigned short* wbfsm = (unsigned short*)(ws + 9846784);   //    8,192 f
    unsigned short* wboff = (unsigned short*)(ws + 9854976);   //   16,384 f
    unsigned short* wbcat = (unsigned short*)(ws + 9871360);   //    4,096 f
    unsigned short* wbdcn = (unsigned short*)(ws + 9875456);   //   36,864 f

    k_prepfs<<<128, 256, 0, stream>>>(feat_s, fsT4);
    k_packall<<<208, 256, 0, stream>>>(W_fsm, W_off, W_cat, W_dcn, W_om,
                                       wbfsm, wboff, wbcat, wbdcn, wb2);

    k12<<<512, 256, 0, stream>>>(feat_l, fsT4, wbfsm, wboff,
                                 s_fsm, b_fsm, s_off, b_off, feat_arm, offT);
    k_om<<<512, 256, 0, stream>>>(offT, wb2, b_om, om_ws);
    k45<<<512, 512, 0, stream>>>(fsT4, om_ws, wbdcn, b_dcn, wbcat,
                                 s_cat, b_cat, feat_arm, feat);
}